// Round 4
// baseline (586.954 us; speedup 1.0000x reference)
//
#include <hip/hip_runtime.h>

#define BB 32
#define CC 129
#define TT 1000
#define DD 256
#define NN 64
#define NLY 4

// ---------------- workspace layout (floats) ----------------
#define OFF_H    0
#define OFF_K    8192000
#define OFF_INV  9232384
#define OFF_MHA  9264384

typedef __attribute__((ext_vector_type(8))) short bf16x8;
typedef __attribute__((ext_vector_type(8))) _Float16 f16x8;
typedef __attribute__((ext_vector_type(4))) float f32x4;
typedef __attribute__((ext_vector_type(16))) float f32x16;

__device__ __forceinline__ unsigned short f2bf(float x) {
    unsigned int u = __float_as_uint(x);
    unsigned int r = (u + 0x7FFF + ((u >> 16) & 1)) >> 16;
    return (unsigned short)r;
}
__device__ __forceinline__ float bf2f(unsigned short b) {
    return __uint_as_float(((unsigned int)b) << 16);
}
__device__ __forceinline__ unsigned short f2h(float x) {
    _Float16 v = (_Float16)x;
    return *(unsigned short*)&v;
}
__device__ __forceinline__ float h2f(unsigned short b) {
    _Float16 v = *(_Float16*)&b;
    return (float)v;
}

// ============ Ad build (block 0) + w_in split-bf16 prep (blocks 1..256) ============
// v5: iterative pivoting is latency-bound (v4: 44us, 1650 cyc/pivot from serially
// dependent bpermute+LDS+barrier per pivot). Eliminated via structure:
//   A = PP^T - 2*strict_lower(PP^T) - 3*diag(i+0.5),  P_i = sqrt(1+2i)
//   => M = I - hA = L - h p p^T,  L lower-triangular, CLOSED FORM.
// Sherman-Morrison: M^-1 = X + beta*u*v^T, X = L^-1. Column j of X via a 3-op
// scalar recurrence per lane (no barriers/shuffles): x_i=(d_ij-2hP_i s)/L_ii,
// s+=P_i x_i. v_j = s_final, p^Tu = su_final fall out of the accumulators.
// Newton polish V<-V(2I-MV) kept: corrects SM rounding to GJ-level accuracy and
// catches any structural bug (absmax would explode).
#define BST 68   // LDS row stride: 68*4 = 272 B, 16B-aligned rows for b128 reads
__global__ __launch_bounds__(256, 1) void k_build_ad(const float* __restrict__ logdt,
                                                     float* __restrict__ P,
                                                     const float* __restrict__ w_in,
                                                     unsigned short* __restrict__ whi,
                                                     unsigned short* __restrict__ wlo) {
    int tid = threadIdx.x;
    if (blockIdx.x != 0) {
        int d = blockIdx.x - 1;      // 0..255
        int c = tid;
        if (c < 136) {
            float v = (c < CC) ? w_in[d * CC + c] : 0.f;
            unsigned short h = f2bf(v);
            whi[d * 136 + c] = h;
            wlo[d * 136 + c] = f2bf(v - bf2f(h));
        }
        return;
    }
    __shared__ __align__(16) float Ms[64 * BST];
    __shared__ __align__(16) float Vs[64 * BST];
    __shared__ __align__(16) float Ws[64 * BST];
    float dt = expf(logdt[0]);
    dt = fminf(fmaxf(dt, 1e-4f), 0.1f);
    float hh = dt * 0.5f;
    int w = tid >> 6, r = tid & 63;
    // ---- stage M (closed form) into LDS for the Newton polish ----
    {
        float Pr = sqrtf(1.f + 2.f * (float)r);
#pragma unroll
        for (int jj = 0; jj < 16; ++jj) {
            int j = w * 16 + jj;
            float av;
            if (r == j) av = -((float)r + 0.5f);
            else { float m = Pr * sqrtf(1.f + 2.f * (float)j); av = (r > j) ? -m : m; }
            Ms[r * BST + j] = ((r == j) ? 1.f : 0.f) - hh * av;
        }
    }
    // ---- wave 0: Sherman-Morrison M^-1, column per lane, zero barriers ----
    if (tid < 64) {
        int lane = tid;
        float x[64], u[64];
        float s = 0.f, su = 0.f;
#pragma unroll
        for (int i = 0; i < 64; ++i) {
            const float Pi = sqrtf(2.f * (float)i + 1.f);          // folds to literal
            float Lii = fmaf(3.f * ((float)i + 0.5f), hh, 1.f);
            float rinv = 1.f / Lii;                                 // indep of chain (ILP)
            float c = 2.f * hh * Pi;
            float del = (lane == i) ? 1.f : 0.f;
            x[i] = (del - c * s) * rinv;
            s = fmaf(Pi, x[i], s);                                  // s_final = v_lane
            u[i] = (Pi - c * su) * rinv;
            su = fmaf(Pi, u[i], su);                                // su_final = p^T u
        }
        float beta = hh / (1.f - hh * su);
        float bv = beta * s;                                        // beta * v_lane
#pragma unroll
        for (int i = 0; i < 64; ++i)
            Vs[i * BST + lane] = fmaf(bv, u[i], x[i]);              // M^-1[i][lane]
    }
    __syncthreads();
    // ---- Newton refine, step A: W = 2I - M*V (4x4 tiles) ----
    {
        int tr = (tid >> 4) << 2, tc = (tid & 15) << 2;
        float acc[4][4];
#pragma unroll
        for (int u = 0; u < 4; ++u)
#pragma unroll
            for (int v = 0; v < 4; ++v) acc[u][v] = 0.f;
        for (int k0 = 0; k0 < 64; k0 += 4) {
            f32x4 av[4], bv[4];
#pragma unroll
            for (int u = 0; u < 4; ++u) av[u] = *(const f32x4*)&Ms[(tr + u) * BST + k0];
#pragma unroll
            for (int kk = 0; kk < 4; ++kk) bv[kk] = *(const f32x4*)&Vs[(k0 + kk) * BST + tc];
#pragma unroll
            for (int u = 0; u < 4; ++u)
#pragma unroll
                for (int kk = 0; kk < 4; ++kk)
#pragma unroll
                    for (int v = 0; v < 4; ++v)
                        acc[u][v] = fmaf(av[u][kk], bv[kk][v], acc[u][v]);
        }
        __syncthreads();
#pragma unroll
        for (int u = 0; u < 4; ++u)
#pragma unroll
            for (int v = 0; v < 4; ++v)
                Ws[(tr + u) * BST + tc + v] =
                    (((tr + u) == (tc + v)) ? 2.f : 0.f) - acc[u][v];
    }
    __syncthreads();
    // ---- Newton refine, step B: Ad = 2*(V*W) - I ; also P[0] = I ----
    {
        int tr = (tid >> 4) << 2, tc = (tid & 15) << 2;
        float acc[4][4];
#pragma unroll
        for (int u = 0; u < 4; ++u)
#pragma unroll
            for (int v = 0; v < 4; ++v) acc[u][v] = 0.f;
        for (int k0 = 0; k0 < 64; k0 += 4) {
            f32x4 av[4], bv[4];
#pragma unroll
            for (int u = 0; u < 4; ++u) av[u] = *(const f32x4*)&Vs[(tr + u) * BST + k0];
#pragma unroll
            for (int kk = 0; kk < 4; ++kk) bv[kk] = *(const f32x4*)&Ws[(k0 + kk) * BST + tc];
#pragma unroll
            for (int u = 0; u < 4; ++u)
#pragma unroll
                for (int kk = 0; kk < 4; ++kk)
#pragma unroll
                    for (int v = 0; v < 4; ++v)
                        acc[u][v] = fmaf(av[u][kk], bv[kk][v], acc[u][v]);
        }
#pragma unroll
        for (int u = 0; u < 4; ++u)
#pragma unroll
            for (int v = 0; v < 4; ++v) {
                int rr = tr + u, cc = tc + v;
                float eye = (rr == cc) ? 1.f : 0.f;
                P[rr * 64 + cc] = eye;
                P[4096 + rr * 64 + cc] = 2.f * acc[u][v] - eye;
            }
    }
}

// ============ single-launch power table: P[j]=Ad^j (j=2..31), Q[i]=Ad^(32i) (i=0..31) ====
// 62 blocks binary-exponentiate independently in LDS. unroll-2 on the k-loop so the
// scheduler overlaps next step's ds_reads with current fmas (1 wave/SIMD here).
#define PLDA 68   // 64+4 pad: row stride 4 banks -> distinct banks for 4-row b128 reads
__device__ __forceinline__ void mm64x(float* D, const float* A, const float* B) {
    int tr = (threadIdx.x >> 4) << 2, tc = (threadIdx.x & 15) << 2;
    float acc[4][4];
#pragma unroll
    for (int u = 0; u < 4; ++u)
#pragma unroll
        for (int v = 0; v < 4; ++v) acc[u][v] = 0.f;
#pragma unroll 2
    for (int k0 = 0; k0 < 64; k0 += 4) {
        f32x4 av[4], bv[4];
#pragma unroll
        for (int u = 0; u < 4; ++u) av[u] = *(const f32x4*)&A[(tr + u) * PLDA + k0];
#pragma unroll
        for (int kk = 0; kk < 4; ++kk) bv[kk] = *(const f32x4*)&B[(k0 + kk) * PLDA + tc];
#pragma unroll
        for (int u = 0; u < 4; ++u)
#pragma unroll
            for (int kk = 0; kk < 4; ++kk)
#pragma unroll
                for (int v = 0; v < 4; ++v)
                    acc[u][v] = fmaf(av[u][kk], bv[kk][v], acc[u][v]);
    }
    __syncthreads();
#pragma unroll
    for (int u = 0; u < 4; ++u)
#pragma unroll
        for (int v = 0; v < 4; ++v) D[(tr + u) * PLDA + tc + v] = acc[u][v];
    __syncthreads();
}

__device__ float* powm(float* U, float* V, const float* base, int e) {
    for (int i = threadIdx.x; i < 4096; i += 256)
        U[(i >> 6) * PLDA + (i & 63)] = base[(i >> 6) * PLDA + (i & 63)];
    __syncthreads();
    float* X = U; float* Y = V;
    for (int bit = 30 - __builtin_clz(e); bit >= 0; --bit) {
        mm64x(Y, X, X); { float* t = X; X = Y; Y = t; }
        if ((e >> bit) & 1) { mm64x(Y, X, base); float* t = X; X = Y; Y = t; }
    }
    return X;
}

__global__ __launch_bounds__(256) void k_powers(float* __restrict__ P, float* __restrict__ Q) {
    __shared__ __align__(16) float AdS[64 * PLDA];
    __shared__ __align__(16) float BaseS[64 * PLDA];
    __shared__ __align__(16) float Ub[64 * PLDA];
    __shared__ __align__(16) float Vb[64 * PLDA];
    int tid = threadIdx.x, bid = blockIdx.x;
    if (bid == 61) {   // Q[0] = I
        for (int i = tid; i < 4096; i += 256) Q[i] = ((i >> 6) == (i & 63)) ? 1.f : 0.f;
        return;
    }
    const float* Ad = P + 4096;
    for (int i = tid; i < 4096; i += 256) AdS[(i >> 6) * PLDA + (i & 63)] = Ad[i];
    __syncthreads();
    float* res;
    float* out;
    if (bid < 30) {                    // P[2+bid] = Ad^(2+bid)
        res = powm(Ub, Vb, AdS, bid + 2);
        out = P + (size_t)(bid + 2) * 4096;
    } else {                           // Q[i] = (Ad^32)^i, i = bid-29 in 1..31
        int iq = bid - 29;
        float* b32 = powm(Ub, Vb, AdS, 32);
        for (int i = tid; i < 4096; i += 256)
            BaseS[(i >> 6) * PLDA + (i & 63)] = b32[(i >> 6) * PLDA + (i & 63)];
        __syncthreads();
        res = powm(Ub, Vb, BaseS, iq);
        out = Q + (size_t)iq * 4096;
    }
    for (int i = tid; i < 4096; i += 256) out[i] = res[(i >> 6) * PLDA + (i & 63)];
}

// ============ L / R ============
__global__ __launch_bounds__(256) void k_lr(const float* __restrict__ P, const float* __restrict__ Q,
                                            const float* __restrict__ s4B, const float* __restrict__ s4C,
                                            float* __restrict__ L, float* __restrict__ R) {
    __shared__ float Ms[4096];
    int l = blockIdx.x >> 6, rem = blockIdx.x & 63, which = rem >> 5, idx = rem & 31;
    const float* M = which ? (P + (size_t)idx * 4096)
                           : (Q + (size_t)idx * 4096);
    for (int i = threadIdx.x; i < 4096; i += 256) Ms[i] = M[i];
    __syncthreads();
    int d = threadIdx.x;
    if (which == 0) {
        float* dst = L + (((size_t)(l * DD + d) * 32 + idx) * 64);
        for (int jc = 0; jc < 8; ++jc) {
            float acc[8];
#pragma unroll
            for (int u = 0; u < 8; ++u) acc[u] = 0.f;
            for (int i = 0; i < 64; ++i) {
                float bv = s4B[(l * NN + i) * DD + d];
#pragma unroll
                for (int u = 0; u < 8; ++u)
                    acc[u] = fmaf(bv, Ms[i * 64 + jc * 8 + u], acc[u]);
            }
#pragma unroll
            for (int u = 0; u < 8; ++u) dst[jc * 8 + u] = acc[u];
        }
    } else {
        float* dst = R + (((size_t)(l * DD + d) * 32 + idx) * 64);
        const float* Cp = s4C + (size_t)(l * DD + d) * NN;
        for (int ic = 0; ic < 8; ++ic) {
            float acc[8];
#pragma unroll
            for (int u = 0; u < 8; ++u) acc[u] = 0.f;
            for (int j = 0; j < 64; ++j) {
                float cv = Cp[j];
#pragma unroll
                for (int u = 0; u < 8; ++u)
                    acc[u] = fmaf(Ms[(ic * 8 + u) * 64 + j], cv, acc[u]);
            }
#pragma unroll
            for (int u = 0; u < 8; ++u) dst[ic * 8 + u] = acc[u];
        }
    }
}

// ============ kernel assembly ============
__global__ __launch_bounds__(256) void k_kker(const float* __restrict__ L, const float* __restrict__ R,
                                              float* __restrict__ kk) {
    __shared__ float Ls[32 * 65], Rs[32 * 65];
    int l = blockIdx.x >> 8, d = blockIdx.x & 255;
    const float* Lp = L + ((size_t)(l * DD + d) * 32) * 64;
    const float* Rp = R + ((size_t)(l * DD + d) * 32) * 64;
    for (int i = threadIdx.x; i < 2048; i += 256) {
        int row = i >> 6, col = i & 63;
        Ls[row * 65 + col] = Lp[i];
        Rs[row * 65 + col] = Rp[i];
    }
    __syncthreads();
    for (int t = threadIdx.x; t < TT; t += 256) {
        int kq = t >> 5, r = t & 31;
        const float* lr = &Ls[kq * 65];
        const float* rr = &Rs[r * 65];
        float a = 0.f;
#pragma unroll 8
        for (int m = 0; m < 64; ++m) a = fmaf(lr[m], rr[m], a);
        kk[(size_t)(l * DD + d) * TT + t] = a * expf(-0.01f * (float)t);
    }
}

// ============ MFMA embed + fused LayerNorm + pos-encoding + invn ============
// v2: 512 threads (8 waves, each 32d x 64t) -> 16 waves/CU (was 8);
// stores reordered (mt,r)-outer / nt-inner so each h-row's 256B span issues
// back-to-back (kills L2 re-dirty writebacks); stats via shfl_xor over q.
__global__ __launch_bounds__(512, 4) void k_embed_mfma(const float* __restrict__ x,
                                                    const unsigned short* __restrict__ whi,
                                                    const unsigned short* __restrict__ wlo,
                                                    const float* __restrict__ w_in,
                                                    const float* __restrict__ b_in,
                                                    const float* __restrict__ lng,
                                                    const float* __restrict__ lnb,
                                                    float* __restrict__ h,
                                                    float* __restrict__ invn) {
    __shared__ unsigned short xs_h[64 * 130], xs_l[64 * 130];
    __shared__ float xlasts[64], w128s[256], biass[256], gs[256], bs[256];
    __shared__ float ps[64][8], ps2[64][8];
    __shared__ float mstat[64], rstat[64];
    int b = blockIdx.y, t0 = blockIdx.x * 64;
    int tid = threadIdx.x;
    for (int i = tid; i < CC * 64; i += 512) {
        int c = i >> 6, tl = i & 63;
        int t = t0 + tl;
        float v = (t < TT) ? x[(size_t)(b * CC + c) * TT + t] : 0.f;
        if (c == 128) {
            xlasts[tl] = v;
        } else {
            unsigned short hh = f2bf(v);
            xs_h[tl * 130 + c] = hh;
            xs_l[tl * 130 + c] = f2bf(v - bf2f(hh));
        }
    }
    if (tid < 256) {
        w128s[tid] = w_in[tid * CC + 128];
        biass[tid] = b_in[tid];
        gs[tid] = lng[tid];
        bs[tid] = lnb[tid];
    }
    __syncthreads();
    int wave = tid >> 6, lane = tid & 63;
    int tn = lane & 15, q = lane >> 4;
    int d0w = wave * 32;
    f32x4 acc[4][2];
#pragma unroll
    for (int nt = 0; nt < 4; ++nt)
#pragma unroll
        for (int mt = 0; mt < 2; ++mt) acc[nt][mt] = (f32x4){0.f, 0.f, 0.f, 0.f};
#pragma unroll
    for (int kc = 0; kc < 4; ++kc) {
        int c0 = kc * 32;
        bf16x8 Ah[2], Al[2];
#pragma unroll
        for (int mt = 0; mt < 2; ++mt) {
            int base = (d0w + mt * 16 + tn) * 136 + c0 + 8 * q;
            Ah[mt] = *(const bf16x8*)&whi[base];
            Al[mt] = *(const bf16x8*)&wlo[base];
        }
#pragma unroll
        for (int nt = 0; nt < 4; ++nt) {
            const unsigned int* ph = (const unsigned int*)&xs_h[(nt * 16 + tn) * 130 + c0 + 8 * q];
            const unsigned int* pl = (const unsigned int*)&xs_l[(nt * 16 + tn) * 130 + c0 + 8 * q];
            union { bf16x8 v; unsigned int u[4]; } Bh, Bl;
            Bh.u[0] = ph[0]; Bh.u[1] = ph[1]; Bh.u[2] = ph[2]; Bh.u[3] = ph[3];
            Bl.u[0] = pl[0]; Bl.u[1] = pl[1]; Bl.u[2] = pl[2]; Bl.u[3] = pl[3];
#pragma unroll
            for (int mt = 0; mt < 2; ++mt) {
                acc[nt][mt] = __builtin_amdgcn_mfma_f32_16x16x32_bf16(Al[mt], Bh.v, acc[nt][mt], 0, 0, 0);
                acc[nt][mt] = __builtin_amdgcn_mfma_f32_16x16x32_bf16(Ah[mt], Bl.v, acc[nt][mt], 0, 0, 0);
                acc[nt][mt] = __builtin_amdgcn_mfma_f32_16x16x32_bf16(Ah[mt], Bh.v, acc[nt][mt], 0, 0, 0);
            }
        }
    }
#pragma unroll
    for (int nt = 0; nt < 4; ++nt) {
        float xl = xlasts[nt * 16 + tn];
        float s = 0.f, s2 = 0.f;
#pragma unroll
        for (int mt = 0; mt < 2; ++mt) {
#pragma unroll
            for (int r = 0; r < 4; ++r) {
                int d = d0w + mt * 16 + 4 * q + r;
                float v = acc[nt][mt][r] + biass[d] + w128s[d] * xl;
                acc[nt][mt][r] = v;
                s += v; s2 = fmaf(v, v, s2);
            }
        }
        s += __shfl_xor(s, 16); s += __shfl_xor(s, 32);
        s2 += __shfl_xor(s2, 16); s2 += __shfl_xor(s2, 32);
        if (q == 0) { ps[nt * 16 + tn][wave] = s; ps2[nt * 16 + tn][wave] = s2; }
    }
    __syncthreads();
    if (tid < 64) {
        float s = 0.f, s2 = 0.f;
#pragma unroll
        for (int k = 0; k < 8; ++k) { s += ps[tid][k]; s2 += ps2[tid][k]; }
        float mean = s * (1.f / 256.f);
        float ex2 = s2 * (1.f / 256.f);
        mstat[tid] = mean;
        rstat[tid] = 1.f / sqrtf(ex2 - mean * mean + 1e-5f);
    }
    __syncthreads();
    float sq[4] = {0.f, 0.f, 0.f, 0.f};
#pragma unroll
    for (int mt = 0; mt < 2; ++mt) {
#pragma unroll
        for (int r = 0; r < 4; ++r) {
            int d = d0w + mt * 16 + 4 * q + r;
            float gd = gs[d], bd = bs[d];
            float freq = expf((float)(d & ~1) * (-9.210340371976184f / 256.f));
            int odd = d & 1;
#pragma unroll
            for (int nt = 0; nt < 4; ++nt) {
                int tl = nt * 16 + tn;
                int t = t0 + tl;
                float o = (acc[nt][mt][r] - mstat[tl]) * rstat[tl] * gd + bd;
                float ang = (float)t * freq;
                o += odd ? cosf(ang) : sinf(ang);
                if (t < TT) h[((size_t)(b * DD + d)) * TT + t] = o;
                sq[nt] = fmaf(o, o, sq[nt]);
            }
        }
    }
#pragma unroll
    for (int nt = 0; nt < 4; ++nt) {
        float s = sq[nt];
        s += __shfl_xor(s, 16); s += __shfl_xor(s, 32);
        if (q == 0) ps[nt * 16 + tn][wave] = s;
    }
    __syncthreads();
    if (tid < 64) {
        int t = t0 + tid;
        if (t < TT) {
            float s = 0.f;
#pragma unroll
            for (int k = 0; k < 8; ++k) s += ps[tid][k];
            invn[b * TT + t] = 1.f / (sqrtf(s) + 1e-8f);
        }
    }
}

// ============ LayerNorm (in-place), single-pass ============
// v2: v1's v[64] register cache was discarded by the compiler (VGPR=48 -> re-read
// of `in` through L2/L3). Cache the block's 64KB tile in LDS instead: exactly one
// global read + one global write. Stats arithmetic order identical to v1.
__global__ __launch_bounds__(256) void k_ln(const float* __restrict__ in, const float* __restrict__ g,
                                            const float* __restrict__ bia, float* __restrict__ out,
                                            float* __restrict__ invn) {
    int b = blockIdx.y, t0 = blockIdx.x * 64;
    int w = threadIdx.x >> 6, lane = threadIdx.x & 63;
    int t = t0 + lane;
    __shared__ float hs[256 * 64];        // [d][t-local], 64 KB
    __shared__ float ps[4][64], ps2[4][64];
    float s = 0.f, s2 = 0.f;
    bool ok = t < TT;
#pragma unroll
    for (int k = 0; k < 64; ++k) {
        int d = w + 4 * k;
        float x = ok ? in[(size_t)(b * DD + d) * TT + t] : 0.f;
        hs[d * 64 + lane] = x;
        s += x; s2 = fmaf(x, x, s2);
    }
    ps[w][lane] = s; ps2[w][lane] = s2;
    __syncthreads();
    float mean = (ps[0][lane] + ps[1][lane] + ps[2][lane] + ps[3][lane]) * (1.f / 256.f);
    float ex2  = (ps2[0][lane] + ps2[1][lane] + ps2[2][lane] + ps2[3][lane]) * (1.f / 256.f);
    float rstd = 1.f / sqrtf(ex2 - mean * mean + 1e-5f);
    float sq = 0.f;
    if (ok) {
#pragma unroll
        for (int k = 0; k < 64; ++k) {
            int d = w + 4 * k;
            float o = (hs[d * 64 + lane] - mean) * rstd * g[d] + bia[d];
            out[(size_t)(b * DD + d) * TT + t] = o;
            sq = fmaf(o, o, sq);
        }
    }
    __syncthreads();
    ps[w][lane] = sq;
    __syncthreads();
    if (w == 0 && ok) {
        float tot = ps[0][lane] + ps[1][lane] + ps[2][lane] + ps[3][lane];
        invn[b * TT + t] = 1.f / (sqrtf(tot) + 1e-8f);
    }
}

__device__ __forceinline__ float gelu_exact(float y) {
    return 0.5f * y * (1.f + erff(y * 0.7071067811865476f));
}

// ============ MFMA conv, 32x32x16 fp16 single (1 MFMA/slab), one block per d ============
// fp16 rounding error is incoherent over K~1000 terms -> conv-out error ~2.5e-5/layer
// (vs 1.35e-3 threshold). Residual ho RE-READ from global (L2-hot) — reconstructing
// it from rounded fp16 would inject 2.4e-4/layer, the only dangerous path.
// Toeplitz B: pair-packed dwords pk[m]=(k~[m]|k~[m-1]) -> 4 aligned b32 per frag.
// A: contiguous fp16 b128. Snake: wave w does groups {w, 15-w} -> 68 D-steps.
#define XS2 1032
__global__ __launch_bounds__(512) void k_conv32(float* __restrict__ h, const float* __restrict__ kk,
                                                const float* __restrict__ invn,
                                                const float* __restrict__ s4D, int layer) {
    __shared__ unsigned short Xs[32 * XS2];
    __shared__ unsigned int pks[1056];
    int d = blockIdx.x;
    int tid = threadIdx.x;
    const float* krow = kk + (size_t)(layer * DD + d) * TT;
    for (int mm = tid; mm < 1056; mm += 512) {
        int m = mm - 32;
        float klo = (m >= 0 && m < TT) ? krow[m] : 0.f;
        float kpr = (m >= 1 && m <= TT) ? krow[m - 1] : 0.f;
        pks[mm] = (unsigned int)f2h(klo) | ((unsigned int)f2h(kpr) << 16);
    }
    for (int ii = tid; ii < 32 * 512; ii += 512) {
        int bb = ii >> 9;
        int tp = (ii & 511) * 2;
        const float* hrow = h + ((size_t)bb * DD + d) * TT;
        const float* ivr = invn + (size_t)bb * TT;
        float v0 = (tp < TT) ? hrow[tp] * ivr[tp] : 0.f;
        float v1 = (tp + 1 < TT) ? hrow[tp + 1] * ivr[tp + 1] : 0.f;
        ((unsigned int*)Xs)[(bb * XS2 + tp) >> 1] = (unsigned int)f2h(v0) | ((unsigned int)f2h(v1) << 16);
    }
    __syncthreads();
    float gate = 1.f / (1.f + expf(-s4D[layer * DD + d]));
    int wave = tid >> 6, lane = tid & 63;
    int nn = lane & 31, kq8 = (lane >> 5) << 3;
    for (int pass = 0; pass < 2; ++pass) {
        int G = pass ? (15 - wave) : wave;
        int jlo = 2 * G;
        f32x16 acc[2];
#pragma unroll
        for (int m = 0; m < 2; ++m)
#pragma unroll
            for (int r = 0; r < 16; ++r) acc[m][r] = 0.f;
        for (int D = 32 * jlo + 32; D >= -16; D -= 16) {
            int S32 = D + nn - kq8 + 32;
            union { f16x8 v; unsigned int u[4]; } bh;
            bh.u[0] = pks[S32];
            bh.u[1] = pks[S32 - 2];
            bh.u[2] = pks[S32 - 4];
            bh.u[3] = pks[S32 - 6];
#pragma unroll
            for (int m = 0; m < 2; ++m) {
                int u0 = (jlo + m) * 32 - D;
                if (u0 >= 0) {
                    const f16x8 ah = *(const f16x8*)&Xs[nn * XS2 + u0 + kq8];
                    acc[m] = __builtin_amdgcn_mfma_f32_32x32x16_f16(ah, bh.v, acc[m], 0, 0, 0);
                }
            }
        }
#pragma unroll
        for (int m = 0; m < 2; ++m) {
            int t = (jlo + m) * 32 + nn;
            if (t < TT) {
#pragma unroll
                for (int r = 0; r < 16; ++r) {
                    int brow = (r & 3) + 8 * (r >> 2) + 4 * (lane >> 5);
                    size_t ix = ((size_t)brow * DD + d) * TT + t;
                    float y = acc[m][r];
                    float xn = h2f(Xs[brow * XS2 + t]);
                    float ho = h[ix];                       // L2-hot re-read (exact residual)
                    h[ix] = gelu_exact(y + xn * gate) + 1.1f * ho;
                }
            }
        }
    }
}

// ============ MHA pooling ============
__global__ __launch_bounds__(256) void k_qprep(const float* __restrict__ cls, const float* __restrict__ inw,
                                               const float* __restrict__ inb, float* __restrict__ qk,
                                               float* __restrict__ qb) {
    __shared__ float Qv[256];
    int j = threadIdx.x;
    float a = inb[j];
    for (int i = 0; i < 256; ++i) a = fmaf(inw[j * DD + i], cls[i], a);
    Qv[j] = a;
    __syncthreads();
    const float scale = 0.17677669529663687f; // 1/sqrt(32)
    for (int idx = threadIdx.x; idx < 8 * 256; idx += 256) {
        int hh = idx >> 8, i = idx & 255;
        float s = 0.f;
        for (int jj = 0; jj < 32; ++jj)
            s = fmaf(Qv[hh * 32 + jj], inw[(DD + hh * 32 + jj) * DD + i], s);
        qk[idx] = s * scale;
    }
    if (threadIdx.x < 8) {
        int hh = threadIdx.x;
        float s = 0.f;
        for (int jj = 0; jj < 32; ++jj)
            s = fmaf(Qv[hh * 32 + jj], inb[DD + hh * 32 + jj], s);
        qb[hh] = s * scale;
    }
}

__global__ __launch_bounds__(128) void k_scores(const float* __restrict__ h, const float* __restrict__ cls,
                                                const float* __restrict__ qkw, const float* __restrict__ qbw,
                                                float* __restrict__ sc) {
    __shared__ float qks[8 * 256];
    int b = blockIdx.y;
    int s = blockIdx.x * 128 + threadIdx.x;
    for (int i = threadIdx.x; i < 2048; i += 128) qks[i] = qkw[i];
    __syncthreads();
    if (s >= TT + 1) return;
    float acc[8];
#pragma unroll
    for (int hh = 0; hh < 8; ++hh) acc[hh] = qbw[hh];
    if (s == 0) {
        for (int i = 0; i < 256; ++i) {
            float v = cls[i];
#pragma unroll
            for (int hh = 0; hh < 8; ++hh) acc[hh] = fmaf(qks[hh * 256 + i], v, acc[hh]);
        }
    } else {
        const float* hb = h + (size_t)b * DD * TT + (s - 1);
        for (int i = 0; i < 256; ++i) {
            float v = hb[(size_t)i * TT];
#pragma unroll
            for (int hh = 0; hh < 8; ++hh) acc[hh] = fmaf(qks[hh * 256 + i], v, acc[hh]);
        }
    }
#pragma unroll
    for (int hh = 0; hh < 8; ++hh) sc[(size_t)(b * 8 + hh) * 1024 + s] = acc[hh];
}

__global__ __launch_bounds__(256) void k_softmax(const float* __restrict__ sc, float* __restrict__ att) {
    int row = blockIdx.x;
    const float* p = sc + (size_t)row * 1024;
    float* o = att + (size_t)row * 1024;
    __shared__ float red[256];
    float m = -3.4e38f;
    for (int s = threadIdx.x; s < TT + 1; s += 256) m = fmaxf(m, p[s]);
    red[threadIdx.x] = m; __syncthreads();
    for (int st = 128; st; st >>= 1) {
        if (threadIdx.x < st) red[threadIdx.x] = fmaxf(red[threadIdx.x], red[threadIdx.x + st]);
        __syncthreads();
    }
    m = red[0]; __syncthreads();
    float sum = 0.f;
    for (int s = threadIdx.x; s < TT + 1; s += 256) {
        float e = expf(p[s] - m);
        o[s] = e; sum += e;
    }
    red[threadIdx.x] = sum; __syncthreads();
    for (int st = 128; st; st >>= 1) {
        if (threadIdx.x < st) red[threadIdx.x] += red[threadIdx.x + st];
        __syncthreads();
    }
    float inv = 1.f / red[0];
    for (int s = threadIdx.x; s < TT + 1; s += 256) o[s] *= inv;
}

// ============ ctx stage 1: t-chunked partials ============
__global__ __launch_bounds__(256) void k_ctx1(const float* __restrict__ h,
                                              const float* __restrict__ att,
                                              float* __restrict__ ctx1) {
    __shared__ float as[8][256];
    int i0 = blockIdx.x * 32, tc = blockIdx.y, b = blockIdx.z;
    int tid = threadIdx.x;
    int sbase = tc * 250 + 1;
    for (int idx = tid; idx < 2048; idx += 256) {
        int hh = idx >> 8, u = idx & 255;
        as[hh][u] = (u < 250) ? att[(size_t)(b * 8 + hh) * 1024 + sbase + u] : 0.f;
    }
    __syncthreads();
    int w = tid >> 6, lane = tid & 63;
    for (int ii = 0; ii < 8; ++ii) {
        int i = i0 + w * 8 + ii;
        const float* hb = h + ((size_t)(b * DD + i)) * TT + tc * 250;
        float acc[8];
#pragma unroll
        for (int hh = 0; hh < 8; ++hh) acc[hh] = 0.f;
        for (int u = lane; u < 250; u += 64) {
            float v = hb[u];
#pragma unroll
            for (int hh = 0; hh < 8; ++hh) acc[hh] = fmaf(as[hh][u], v, acc[hh]);
        }
#pragma unroll
        for (int off = 32; off; off >>= 1)
#pragma unroll
            for (int hh = 0; hh < 8; ++hh) acc[hh] += __shfl_down(acc[hh], off);
        if (lane == 0) {
#pragma unroll
            for (int hh = 0; hh < 8; ++hh)
                ctx1[(((size_t)tc * BB + b) * 8 + hh) * DD + i] = acc[hh];
        }
    }
}

// ============ head: reduce ctx partials + cls term, then MLP ============
__global__ __launch_bounds__(256) void k_head(const float* __restrict__ ctx1,
                                              const float* __restrict__ att,
                                              const float* __restrict__ cls,
                                              const float* __restrict__ inw,
                                              const float* __restrict__ inb, const float* __restrict__ outw,
                                              const float* __restrict__ outb, const float* __restrict__ w1,
                                              const float* __restrict__ b1, const float* __restrict__ w2,
                                              const float* __restrict__ b2, float* __restrict__ out) {
    int b = blockIdx.x;
    __shared__ float cs[2048], ao[256], po[256], hid[128];
    int j = threadIdx.x;
    {
        float cv = cls[j];
#pragma unroll
        for (int hh = 0; hh < 8; ++hh) {
            float a = att[(size_t)(b * 8 + hh) * 1024] * cv;
#pragma unroll
            for (int tc = 0; tc < 4; ++tc)
                a += ctx1[(((size_t)tc * BB + b) * 8 + hh) * DD + j];
            cs[hh * 256 + j] = a;
        }
    }
    __syncthreads();
    {
        int hh = j >> 5;
        float a = inb[2 * DD + j];
        const float* wv = inw + (size_t)(2 * DD + j) * DD;
        for (int i = 0; i < 256; ++i) a = fmaf(wv[i], cs[hh * 256 + i], a);
        ao[j] = a;
    }
    __syncthreads();
    {
        float a = outb[j];
        for (int i = 0; i < 256; ++i) a = fmaf(outw[j * DD + i], ao[i], a);
        po[j] = a;
    }
    __syncthreads();
    if (j < 128) {
        float a = b1[j];
        for (int i = 0; i < 256; ++i) a = fmaf(w1[j * 256 + i], po[i], a);
        hid[j] = fmaxf(a, 0.f);
    }
    __syncthreads();
    if (j == 0) {
        float a = b2[0];
        for (int i = 0; i < 128; ++i) a = fmaf(w2[i], hid[i], a);
        out[b] = a;
    }
}

extern "C" void kernel_launch(void* const* d_in, const int* in_sizes, int n_in,
                              void* d_out, int out_size, void* d_ws, size_t ws_size,
                              hipStream_t stream) {
    (void)in_sizes; (void)n_in; (void)out_size; (void)ws_size;
    const float* x        = (const float*)d_in[0];
    const float* w_in     = (const float*)d_in[1];
    const float* b_in     = (const float*)d_in[2];
    const float* ln_in_g  = (const float*)d_in[3];
    const float* ln_in_b  = (const float*)d_in[4];
    const float* s4B      = (const float*)d_in[5];
    const float* s4C      = (const float*)d_in[6];
    const float* s4logdt  = (const float*)d_in[7];
    const float* s4D      = (const float*)d_in[8];
    const float* ln_g     = (const float*)d_in[9];
    const float* ln_b     = (const float*)d_in[10];
    const float* cls      = (const float*)d_in[11];
    const float* mha_in_w = (const float*)d_in[12];
    const float* mha_in_b = (const float*)d_in[13];
    const float* mha_out_w= (const float*)d_in[14];
    const float* mha_out_b= (const float*)d_in[15];
    const float* head_w1  = (const float*)d_in[16];
    const float* head_b1  = (const float*)d_in[17];
    const float* head_w2  = (const float*)d_in[18];
    const float* head_b2  = (const float*)d_in[19];

    float* ws   = (float*)d_ws;
    float* h    = ws + OFF_H;
    float* kker = ws + OFF_K;
    float* invn = ws + OFF_INV;
    float* P  = h;                 // 33 * 4096
    float* Q  = h + 540672;        // 32 * 4096
    float* Lb = h + 1064960;
    float* Rb = h + 3162112;
    float* qkb  = ws + OFF_MHA;
    float* qbb  = qkb + 2048;
    float* scb  = qbb + 16;        // reused: whi/wlo (pre-embed), ctx1 (post-softmax)
    float* attb = scb + 262144;
    unsigned short* whi = (unsigned short*)scb;
    unsigned short* wlo = whi + 256 * 136;
    float* ctx1b = scb;

    k_build_ad<<<dim3(257), dim3(256), 0, stream>>>(s4logdt, P, w_in, whi, wlo);
    k_powers<<<dim3(62), dim3(256), 0, stream>>>(P, Q);
    k_lr<<<dim3(NLY * 64), dim3(256), 0, stream>>>(P, Q, s4B, s4C, Lb, Rb);
    k_kker<<<dim3(NLY * 256), dim3(256), 0, stream>>>(Lb, Rb, kker);

    k_embed_mfma<<<dim3(16, BB), dim3(512), 0, stream>>>(x, whi, wlo, w_in, b_in,
                                                         ln_in_g, ln_in_b, h, invn);

    for (int l = 0; l < NLY; ++l) {
        k_conv32<<<dim3(DD), dim3(512), 0, stream>>>(h, kker, invn, s4D, l);
        k_ln<<<dim3(16, BB), dim3(256), 0, stream>>>(h, ln_g + l * DD, ln_b + l * DD, h, invn);
    }

    k_qprep<<<dim3(1), dim3(256), 0, stream>>>(cls, mha_in_w, mha_in_b, qkb, qbb);
    k_scores<<<dim3(8, BB), dim3(128), 0, stream>>>(h, cls, qkb, qbb, scb);
    k_softmax<<<dim3(256), dim3(256), 0, stream>>>(scb, attb);
    k_ctx1<<<dim3(8, 4, BB), dim3(256), 0, stream>>>(h, attb, ctx1b);
    k_head<<<dim3(BB), dim3(256), 0, stream>>>(ctx1b, attb, cls, mha_in_w, mha_in_b,
                                               mha_out_w, mha_out_b,
                                               head_w1, head_b1, head_w2, head_b2, (float*)d_out);
}

// Round 7
// 536.921 us; speedup vs baseline: 1.0932x; 1.0932x over previous
//
#include <hip/hip_runtime.h>

#define BB 32
#define CC 129
#define TT 1000
#define DD 256
#define NN 64
#define NLY 4

// ---------------- workspace layout (floats) ----------------
#define OFF_H    0
#define OFF_K    8192000
#define OFF_INV  9232384
#define OFF_MHA  9264384

typedef __attribute__((ext_vector_type(8))) short bf16x8;
typedef __attribute__((ext_vector_type(8))) _Float16 f16x8;
typedef __attribute__((ext_vector_type(4))) float f32x4;
typedef __attribute__((ext_vector_type(16))) float f32x16;

__device__ __forceinline__ unsigned short f2bf(float x) {
    unsigned int u = __float_as_uint(x);
    unsigned int r = (u + 0x7FFF + ((u >> 16) & 1)) >> 16;
    return (unsigned short)r;
}
__device__ __forceinline__ float bf2f(unsigned short b) {
    return __uint_as_float(((unsigned int)b) << 16);
}
__device__ __forceinline__ unsigned short f2h(float x) {
    _Float16 v = (_Float16)x;
    return *(unsigned short*)&v;
}
__device__ __forceinline__ float h2f(unsigned short b) {
    _Float16 v = *(_Float16*)&b;
    return (float)v;
}

// ============ Ad build (block 0) + w_in split-bf16 prep (blocks 1..256) ============
// v5: closed-form Sherman-Morrison + Newton polish. HW-verified in R4 (absmax 0).
#define BST 68
__global__ __launch_bounds__(256, 1) void k_build_ad(const float* __restrict__ logdt,
                                                     float* __restrict__ P,
                                                     const float* __restrict__ w_in,
                                                     unsigned short* __restrict__ whi,
                                                     unsigned short* __restrict__ wlo) {
    int tid = threadIdx.x;
    if (blockIdx.x != 0) {
        int d = blockIdx.x - 1;      // 0..255
        int c = tid;
        if (c < 136) {
            float v = (c < CC) ? w_in[d * CC + c] : 0.f;
            unsigned short h = f2bf(v);
            whi[d * 136 + c] = h;
            wlo[d * 136 + c] = f2bf(v - bf2f(h));
        }
        return;
    }
    __shared__ __align__(16) float Ms[64 * BST];
    __shared__ __align__(16) float Vs[64 * BST];
    __shared__ __align__(16) float Ws[64 * BST];
    float dt = expf(logdt[0]);
    dt = fminf(fmaxf(dt, 1e-4f), 0.1f);
    float hh = dt * 0.5f;
    int w = tid >> 6, r = tid & 63;
    {
        float Pr = sqrtf(1.f + 2.f * (float)r);
#pragma unroll
        for (int jj = 0; jj < 16; ++jj) {
            int j = w * 16 + jj;
            float av;
            if (r == j) av = -((float)r + 0.5f);
            else { float m = Pr * sqrtf(1.f + 2.f * (float)j); av = (r > j) ? -m : m; }
            Ms[r * BST + j] = ((r == j) ? 1.f : 0.f) - hh * av;
        }
    }
    if (tid < 64) {
        int lane = tid;
        float x[64], u[64];
        float s = 0.f, su = 0.f;
#pragma unroll
        for (int i = 0; i < 64; ++i) {
            const float Pi = sqrtf(2.f * (float)i + 1.f);
            float Lii = fmaf(3.f * ((float)i + 0.5f), hh, 1.f);
            float rinv = 1.f / Lii;
            float c = 2.f * hh * Pi;
            float del = (lane == i) ? 1.f : 0.f;
            x[i] = (del - c * s) * rinv;
            s = fmaf(Pi, x[i], s);
            u[i] = (Pi - c * su) * rinv;
            su = fmaf(Pi, u[i], su);
        }
        float beta = hh / (1.f - hh * su);
        float bv = beta * s;
#pragma unroll
        for (int i = 0; i < 64; ++i)
            Vs[i * BST + lane] = fmaf(bv, u[i], x[i]);
    }
    __syncthreads();
    // ---- Newton refine, step A: W = 2I - M*V ----
    {
        int tr = (tid >> 4) << 2, tc = (tid & 15) << 2;
        float acc[4][4];
#pragma unroll
        for (int u = 0; u < 4; ++u)
#pragma unroll
            for (int v = 0; v < 4; ++v) acc[u][v] = 0.f;
        for (int k0 = 0; k0 < 64; k0 += 4) {
            f32x4 av[4], bv[4];
#pragma unroll
            for (int u = 0; u < 4; ++u) av[u] = *(const f32x4*)&Ms[(tr + u) * BST + k0];
#pragma unroll
            for (int kk = 0; kk < 4; ++kk) bv[kk] = *(const f32x4*)&Vs[(k0 + kk) * BST + tc];
#pragma unroll
            for (int u = 0; u < 4; ++u)
#pragma unroll
                for (int kk = 0; kk < 4; ++kk)
#pragma unroll
                    for (int v = 0; v < 4; ++v)
                        acc[u][v] = fmaf(av[u][kk], bv[kk][v], acc[u][v]);
        }
        __syncthreads();
#pragma unroll
        for (int u = 0; u < 4; ++u)
#pragma unroll
            for (int v = 0; v < 4; ++v)
                Ws[(tr + u) * BST + tc + v] =
                    (((tr + u) == (tc + v)) ? 2.f : 0.f) - acc[u][v];
    }
    __syncthreads();
    // ---- Newton refine, step B: Ad = 2*(V*W) - I ; also P[0] = I ----
    {
        int tr = (tid >> 4) << 2, tc = (tid & 15) << 2;
        float acc[4][4];
#pragma unroll
        for (int u = 0; u < 4; ++u)
#pragma unroll
            for (int v = 0; v < 4; ++v) acc[u][v] = 0.f;
        for (int k0 = 0; k0 < 64; k0 += 4) {
            f32x4 av[4], bv[4];
#pragma unroll
            for (int u = 0; u < 4; ++u) av[u] = *(const f32x4*)&Vs[(tr + u) * BST + k0];
#pragma unroll
            for (int kk = 0; kk < 4; ++kk) bv[kk] = *(const f32x4*)&Ws[(k0 + kk) * BST + tc];
#pragma unroll
            for (int u = 0; u < 4; ++u)
#pragma unroll
                for (int kk = 0; kk < 4; ++kk)
#pragma unroll
                    for (int v = 0; v < 4; ++v)
                        acc[u][v] = fmaf(av[u][kk], bv[kk][v], acc[u][v]);
        }
#pragma unroll
        for (int u = 0; u < 4; ++u)
#pragma unroll
            for (int v = 0; v < 4; ++v) {
                int rr = tr + u, cc = tc + v;
                float eye = (rr == cc) ? 1.f : 0.f;
                P[rr * 64 + cc] = eye;
                P[4096 + rr * 64 + cc] = 2.f * acc[u][v] - eye;
            }
    }
}

// ============ single-launch power table: P[j]=Ad^j (j=2..31), Q[i]=Ad^(32i) (i=0..31) ====
#define PLDA 68
__device__ __forceinline__ void mm64x(float* D, const float* A, const float* B) {
    int tr = (threadIdx.x >> 4) << 2, tc = (threadIdx.x & 15) << 2;
    float acc[4][4];
#pragma unroll
    for (int u = 0; u < 4; ++u)
#pragma unroll
        for (int v = 0; v < 4; ++v) acc[u][v] = 0.f;
#pragma unroll 2
    for (int k0 = 0; k0 < 64; k0 += 4) {
        f32x4 av[4], bv[4];
#pragma unroll
        for (int u = 0; u < 4; ++u) av[u] = *(const f32x4*)&A[(tr + u) * PLDA + k0];
#pragma unroll
        for (int kk = 0; kk < 4; ++kk) bv[kk] = *(const f32x4*)&B[(k0 + kk) * PLDA + tc];
#pragma unroll
        for (int u = 0; u < 4; ++u)
#pragma unroll
            for (int kk = 0; kk < 4; ++kk)
#pragma unroll
                for (int v = 0; v < 4; ++v)
                    acc[u][v] = fmaf(av[u][kk], bv[kk][v], acc[u][v]);
    }
    __syncthreads();
#pragma unroll
    for (int u = 0; u < 4; ++u)
#pragma unroll
        for (int v = 0; v < 4; ++v) D[(tr + u) * PLDA + tc + v] = acc[u][v];
    __syncthreads();
}

__device__ float* powm(float* U, float* V, const float* base, int e) {
    for (int i = threadIdx.x; i < 4096; i += 256)
        U[(i >> 6) * PLDA + (i & 63)] = base[(i >> 6) * PLDA + (i & 63)];
    __syncthreads();
    float* X = U; float* Y = V;
    for (int bit = 30 - __builtin_clz(e); bit >= 0; --bit) {
        mm64x(Y, X, X); { float* t = X; X = Y; Y = t; }
        if ((e >> bit) & 1) { mm64x(Y, X, base); float* t = X; X = Y; Y = t; }
    }
    return X;
}

__global__ __launch_bounds__(256) void k_powers(float* __restrict__ P, float* __restrict__ Q) {
    __shared__ __align__(16) float AdS[64 * PLDA];
    __shared__ __align__(16) float BaseS[64 * PLDA];
    __shared__ __align__(16) float Ub[64 * PLDA];
    __shared__ __align__(16) float Vb[64 * PLDA];
    int tid = threadIdx.x, bid = blockIdx.x;
    if (bid == 61) {   // Q[0] = I
        for (int i = tid; i < 4096; i += 256) Q[i] = ((i >> 6) == (i & 63)) ? 1.f : 0.f;
        return;
    }
    const float* Ad = P + 4096;
    for (int i = tid; i < 4096; i += 256) AdS[(i >> 6) * PLDA + (i & 63)] = Ad[i];
    __syncthreads();
    float* res;
    float* out;
    if (bid < 30) {                    // P[2+bid] = Ad^(2+bid)
        res = powm(Ub, Vb, AdS, bid + 2);
        out = P + (size_t)(bid + 2) * 4096;
    } else {                           // Q[i] = (Ad^32)^i, i = bid-29 in 1..31
        int iq = bid - 29;
        float* b32 = powm(Ub, Vb, AdS, 32);
        for (int i = tid; i < 4096; i += 256)
            BaseS[(i >> 6) * PLDA + (i & 63)] = b32[(i >> 6) * PLDA + (i & 63)];
        __syncthreads();
        res = powm(Ub, Vb, BaseS, iq);
        out = Q + (size_t)iq * 4096;
    }
    for (int i = tid; i < 4096; i += 256) out[i] = res[(i >> 6) * PLDA + (i & 63)];
}

// ============ L / R ============
__global__ __launch_bounds__(256) void k_lr(const float* __restrict__ P, const float* __restrict__ Q,
                                            const float* __restrict__ s4B, const float* __restrict__ s4C,
                                            float* __restrict__ L, float* __restrict__ R) {
    __shared__ float Ms[4096];
    int l = blockIdx.x >> 6, rem = blockIdx.x & 63, which = rem >> 5, idx = rem & 31;
    const float* M = which ? (P + (size_t)idx * 4096)
                           : (Q + (size_t)idx * 4096);
    for (int i = threadIdx.x; i < 4096; i += 256) Ms[i] = M[i];
    __syncthreads();
    int d = threadIdx.x;
    if (which == 0) {
        float* dst = L + (((size_t)(l * DD + d) * 32 + idx) * 64);
        for (int jc = 0; jc < 8; ++jc) {
            float acc[8];
#pragma unroll
            for (int u = 0; u < 8; ++u) acc[u] = 0.f;
            for (int i = 0; i < 64; ++i) {
                float bv = s4B[(l * NN + i) * DD + d];
#pragma unroll
                for (int u = 0; u < 8; ++u)
                    acc[u] = fmaf(bv, Ms[i * 64 + jc * 8 + u], acc[u]);
            }
#pragma unroll
            for (int u = 0; u < 8; ++u) dst[jc * 8 + u] = acc[u];
        }
    } else {
        float* dst = R + (((size_t)(l * DD + d) * 32 + idx) * 64);
        const float* Cp = s4C + (size_t)(l * DD + d) * NN;
        for (int ic = 0; ic < 8; ++ic) {
            float acc[8];
#pragma unroll
            for (int u = 0; u < 8; ++u) acc[u] = 0.f;
            for (int j = 0; j < 64; ++j) {
                float cv = Cp[j];
#pragma unroll
                for (int u = 0; u < 8; ++u)
                    acc[u] = fmaf(Ms[(ic * 8 + u) * 64 + j], cv, acc[u]);
            }
#pragma unroll
            for (int u = 0; u < 8; ++u) dst[ic * 8 + u] = acc[u];
        }
    }
}

// ============ kernel assembly ============
__global__ __launch_bounds__(256) void k_kker(const float* __restrict__ L, const float* __restrict__ R,
                                              float* __restrict__ kk) {
    __shared__ float Ls[32 * 65], Rs[32 * 65];
    int l = blockIdx.x >> 8, d = blockIdx.x & 255;
    const float* Lp = L + ((size_t)(l * DD + d) * 32) * 64;
    const float* Rp = R + ((size_t)(l * DD + d) * 32) * 64;
    for (int i = threadIdx.x; i < 2048; i += 256) {
        int row = i >> 6, col = i & 63;
        Ls[row * 65 + col] = Lp[i];
        Rs[row * 65 + col] = Rp[i];
    }
    __syncthreads();
    for (int t = threadIdx.x; t < TT; t += 256) {
        int kq = t >> 5, r = t & 31;
        const float* lr = &Ls[kq * 65];
        const float* rr = &Rs[r * 65];
        float a = 0.f;
#pragma unroll 8
        for (int m = 0; m < 64; ++m) a = fmaf(lr[m], rr[m], a);
        kk[(size_t)(l * DD + d) * TT + t] = a * expf(-0.01f * (float)t);
    }
}

// ============ MFMA embed + fused LayerNorm + pos-encoding + invn ============
__global__ __launch_bounds__(512, 4) void k_embed_mfma(const float* __restrict__ x,
                                                    const unsigned short* __restrict__ whi,
                                                    const unsigned short* __restrict__ wlo,
                                                    const float* __restrict__ w_in,
                                                    const float* __restrict__ b_in,
                                                    const float* __restrict__ lng,
                                                    const float* __restrict__ lnb,
                                                    float* __restrict__ h,
                                                    float* __restrict__ invn) {
    __shared__ unsigned short xs_h[64 * 130], xs_l[64 * 130];
    __shared__ float xlasts[64], w128s[256], biass[256], gs[256], bs[256];
    __shared__ float ps[64][8], ps2[64][8];
    __shared__ float mstat[64], rstat[64];
    int b = blockIdx.y, t0 = blockIdx.x * 64;
    int tid = threadIdx.x;
    for (int i = tid; i < CC * 64; i += 512) {
        int c = i >> 6, tl = i & 63;
        int t = t0 + tl;
        float v = (t < TT) ? x[(size_t)(b * CC + c) * TT + t] : 0.f;
        if (c == 128) {
            xlasts[tl] = v;
        } else {
            unsigned short hh = f2bf(v);
            xs_h[tl * 130 + c] = hh;
            xs_l[tl * 130 + c] = f2bf(v - bf2f(hh));
        }
    }
    if (tid < 256) {
        w128s[tid] = w_in[tid * CC + 128];
        biass[tid] = b_in[tid];
        gs[tid] = lng[tid];
        bs[tid] = lnb[tid];
    }
    __syncthreads();
    int wave = tid >> 6, lane = tid & 63;
    int tn = lane & 15, q = lane >> 4;
    int d0w = wave * 32;
    f32x4 acc[4][2];
#pragma unroll
    for (int nt = 0; nt < 4; ++nt)
#pragma unroll
        for (int mt = 0; mt < 2; ++mt) acc[nt][mt] = (f32x4){0.f, 0.f, 0.f, 0.f};
#pragma unroll
    for (int kc = 0; kc < 4; ++kc) {
        int c0 = kc * 32;
        bf16x8 Ah[2], Al[2];
#pragma unroll
        for (int mt = 0; mt < 2; ++mt) {
            int base = (d0w + mt * 16 + tn) * 136 + c0 + 8 * q;
            Ah[mt] = *(const bf16x8*)&whi[base];
            Al[mt] = *(const bf16x8*)&wlo[base];
        }
#pragma unroll
        for (int nt = 0; nt < 4; ++nt) {
            const unsigned int* ph = (const unsigned int*)&xs_h[(nt * 16 + tn) * 130 + c0 + 8 * q];
            const unsigned int* pl = (const unsigned int*)&xs_l[(nt * 16 + tn) * 130 + c0 + 8 * q];
            union { bf16x8 v; unsigned int u[4]; } Bh, Bl;
            Bh.u[0] = ph[0]; Bh.u[1] = ph[1]; Bh.u[2] = ph[2]; Bh.u[3] = ph[3];
            Bl.u[0] = pl[0]; Bl.u[1] = pl[1]; Bl.u[2] = pl[2]; Bl.u[3] = pl[3];
#pragma unroll
            for (int mt = 0; mt < 2; ++mt) {
                acc[nt][mt] = __builtin_amdgcn_mfma_f32_16x16x32_bf16(Al[mt], Bh.v, acc[nt][mt], 0, 0, 0);
                acc[nt][mt] = __builtin_amdgcn_mfma_f32_16x16x32_bf16(Ah[mt], Bl.v, acc[nt][mt], 0, 0, 0);
                acc[nt][mt] = __builtin_amdgcn_mfma_f32_16x16x32_bf16(Ah[mt], Bh.v, acc[nt][mt], 0, 0, 0);
            }
        }
    }
#pragma unroll
    for (int nt = 0; nt < 4; ++nt) {
        float xl = xlasts[nt * 16 + tn];
        float s = 0.f, s2 = 0.f;
#pragma unroll
        for (int mt = 0; mt < 2; ++mt) {
#pragma unroll
            for (int r = 0; r < 4; ++r) {
                int d = d0w + mt * 16 + 4 * q + r;
                float v = acc[nt][mt][r] + biass[d] + w128s[d] * xl;
                acc[nt][mt][r] = v;
                s += v; s2 = fmaf(v, v, s2);
            }
        }
        s += __shfl_xor(s, 16); s += __shfl_xor(s, 32);
        s2 += __shfl_xor(s2, 16); s2 += __shfl_xor(s2, 32);
        if (q == 0) { ps[nt * 16 + tn][wave] = s; ps2[nt * 16 + tn][wave] = s2; }
    }
    __syncthreads();
    if (tid < 64) {
        float s = 0.f, s2 = 0.f;
#pragma unroll
        for (int k = 0; k < 8; ++k) { s += ps[tid][k]; s2 += ps2[tid][k]; }
        float mean = s * (1.f / 256.f);
        float ex2 = s2 * (1.f / 256.f);
        mstat[tid] = mean;
        rstat[tid] = 1.f / sqrtf(ex2 - mean * mean + 1e-5f);
    }
    __syncthreads();
    float sq[4] = {0.f, 0.f, 0.f, 0.f};
#pragma unroll
    for (int mt = 0; mt < 2; ++mt) {
#pragma unroll
        for (int r = 0; r < 4; ++r) {
            int d = d0w + mt * 16 + 4 * q + r;
            float gd = gs[d], bd = bs[d];
            float freq = expf((float)(d & ~1) * (-9.210340371976184f / 256.f));
            int odd = d & 1;
#pragma unroll
            for (int nt = 0; nt < 4; ++nt) {
                int tl = nt * 16 + tn;
                int t = t0 + tl;
                float o = (acc[nt][mt][r] - mstat[tl]) * rstat[tl] * gd + bd;
                float ang = (float)t * freq;
                o += odd ? cosf(ang) : sinf(ang);
                if (t < TT) h[((size_t)(b * DD + d)) * TT + t] = o;
                sq[nt] = fmaf(o, o, sq[nt]);
            }
        }
    }
#pragma unroll
    for (int nt = 0; nt < 4; ++nt) {
        float s = sq[nt];
        s += __shfl_xor(s, 16); s += __shfl_xor(s, 32);
        if (q == 0) ps[nt * 16 + tn][wave] = s;
    }
    __syncthreads();
    if (tid < 64) {
        int t = t0 + tid;
        if (t < TT) {
            float s = 0.f;
#pragma unroll
            for (int k = 0; k < 8; ++k) s += ps[tid][k];
            invn[b * TT + t] = 1.f / (sqrtf(s) + 1e-8f);
        }
    }
}

// ============ LayerNorm (in-place), single-pass ============
// v1 form (HW-verified R1-R3): compiler re-read of `in` is L2-hot and nearly free.
__global__ __launch_bounds__(256) void k_ln(const float* __restrict__ in, const float* __restrict__ g,
                                            const float* __restrict__ bia, float* __restrict__ out,
                                            float* __restrict__ invn) {
    int b = blockIdx.y, t0 = blockIdx.x * 64;
    int w = threadIdx.x >> 6, lane = threadIdx.x & 63;
    int t = t0 + lane;
    __shared__ float ps[4][64], ps2[4][64];
    float v[64];
    float s = 0.f, s2 = 0.f;
    bool ok = t < TT;
#pragma unroll
    for (int k = 0; k < 64; ++k) {
        float x = ok ? in[(size_t)(b * DD + (w + 4 * k)) * TT + t] : 0.f;
        v[k] = x;
        s += x; s2 = fmaf(x, x, s2);
    }
    ps[w][lane] = s; ps2[w][lane] = s2;
    __syncthreads();
    float mean = (ps[0][lane] + ps[1][lane] + ps[2][lane] + ps[3][lane]) * (1.f / 256.f);
    float ex2  = (ps2[0][lane] + ps2[1][lane] + ps2[2][lane] + ps2[3][lane]) * (1.f / 256.f);
    float rstd = 1.f / sqrtf(ex2 - mean * mean + 1e-5f);
    float sq = 0.f;
    if (ok) {
#pragma unroll
        for (int k = 0; k < 64; ++k) {
            int d = w + 4 * k;
            float o = (v[k] - mean) * rstd * g[d] + bia[d];
            out[(size_t)(b * DD + d) * TT + t] = o;
            sq = fmaf(o, o, sq);
        }
    }
    __syncthreads();
    ps[w][lane] = sq;
    __syncthreads();
    if (w == 0 && ok) {
        float tot = ps[0][lane] + ps[1][lane] + ps[2][lane] + ps[3][lane];
        invn[b * TT + t] = 1.f / (sqrtf(tot) + 1e-8f);
    }
}

__device__ __forceinline__ float gelu_exact(float y) {
    return 0.5f * y * (1.f + erff(y * 0.7071067811865476f));
}

// ============ MFMA conv v1 (HW-verified R1-R4): 32 batches, one block per d ============
// v2 (16-batch split) correlated with 2x container failure; reverted pending evidence.
#define XS2 1032
__global__ __launch_bounds__(512) void k_conv32(float* __restrict__ h, const float* __restrict__ kk,
                                                const float* __restrict__ invn,
                                                const float* __restrict__ s4D, int layer) {
    __shared__ unsigned short Xs[32 * XS2];
    __shared__ unsigned int pks[1056];
    int d = blockIdx.x;
    int tid = threadIdx.x;
    const float* krow = kk + (size_t)(layer * DD + d) * TT;
    for (int mm = tid; mm < 1056; mm += 512) {
        int m = mm - 32;
        float klo = (m >= 0 && m < TT) ? krow[m] : 0.f;
        float kpr = (m >= 1 && m <= TT) ? krow[m - 1] : 0.f;
        pks[mm] = (unsigned int)f2h(klo) | ((unsigned int)f2h(kpr) << 16);
    }
    for (int ii = tid; ii < 32 * 512; ii += 512) {
        int bb = ii >> 9;
        int tp = (ii & 511) * 2;
        const float* hrow = h + ((size_t)bb * DD + d) * TT;
        const float* ivr = invn + (size_t)bb * TT;
        float v0 = (tp < TT) ? hrow[tp] * ivr[tp] : 0.f;
        float v1 = (tp + 1 < TT) ? hrow[tp + 1] * ivr[tp + 1] : 0.f;
        ((unsigned int*)Xs)[(bb * XS2 + tp) >> 1] = (unsigned int)f2h(v0) | ((unsigned int)f2h(v1) << 16);
    }
    __syncthreads();
    float gate = 1.f / (1.f + expf(-s4D[layer * DD + d]));
    int wave = tid >> 6, lane = tid & 63;
    int nn = lane & 31, kq8 = (lane >> 5) << 3;
    for (int pass = 0; pass < 2; ++pass) {
        int G = pass ? (15 - wave) : wave;
        int jlo = 2 * G;
        f32x16 acc[2];
#pragma unroll
        for (int m = 0; m < 2; ++m)
#pragma unroll
            for (int r = 0; r < 16; ++r) acc[m][r] = 0.f;
        for (int D = 32 * jlo + 32; D >= -16; D -= 16) {
            int S32 = D + nn - kq8 + 32;
            union { f16x8 v; unsigned int u[4]; } bh;
            bh.u[0] = pks[S32];
            bh.u[1] = pks[S32 - 2];
            bh.u[2] = pks[S32 - 4];
            bh.u[3] = pks[S32 - 6];
#pragma unroll
            for (int m = 0; m < 2; ++m) {
                int u0 = (jlo + m) * 32 - D;
                if (u0 >= 0) {
                    const f16x8 ah = *(const f16x8*)&Xs[nn * XS2 + u0 + kq8];
                    acc[m] = __builtin_amdgcn_mfma_f32_32x32x16_f16(ah, bh.v, acc[m], 0, 0, 0);
                }
            }
        }
#pragma unroll
        for (int m = 0; m < 2; ++m) {
            int t = (jlo + m) * 32 + nn;
            if (t < TT) {
#pragma unroll
                for (int r = 0; r < 16; ++r) {
                    int brow = (r & 3) + 8 * (r >> 2) + 4 * (lane >> 5);
                    size_t ix = ((size_t)brow * DD + d) * TT + t;
                    float y = acc[m][r];
                    float xn = h2f(Xs[brow * XS2 + t]);
                    float ho = h[ix];                       // L2-hot re-read (exact residual)
                    h[ix] = gelu_exact(y + xn * gate) + 1.1f * ho;
                }
            }
        }
    }
}

// ============ MHA pooling ============
__global__ __launch_bounds__(256) void k_qprep(const float* __restrict__ cls, const float* __restrict__ inw,
                                               const float* __restrict__ inb, float* __restrict__ qk,
                                               float* __restrict__ qb) {
    __shared__ float Qv[256];
    int j = threadIdx.x;
    float a = inb[j];
    for (int i = 0; i < 256; ++i) a = fmaf(inw[j * DD + i], cls[i], a);
    Qv[j] = a;
    __syncthreads();
    const float scale = 0.17677669529663687f; // 1/sqrt(32)
    for (int idx = threadIdx.x; idx < 8 * 256; idx += 256) {
        int hh = idx >> 8, i = idx & 255;
        float s = 0.f;
        for (int jj = 0; jj < 32; ++jj)
            s = fmaf(Qv[hh * 32 + jj], inw[(DD + hh * 32 + jj) * DD + i], s);
        qk[idx] = s * scale;
    }
    if (threadIdx.x < 8) {
        int hh = threadIdx.x;
        float s = 0.f;
        for (int jj = 0; jj < 32; ++jj)
            s = fmaf(Qv[hh * 32 + jj], inb[DD + hh * 32 + jj], s);
        qb[hh] = s * scale;
    }
}

__global__ __launch_bounds__(128) void k_scores(const float* __restrict__ h, const float* __restrict__ cls,
                                                const float* __restrict__ qkw, const float* __restrict__ qbw,
                                                float* __restrict__ sc) {
    __shared__ float qks[8 * 256];
    int b = blockIdx.y;
    int s = blockIdx.x * 128 + threadIdx.x;
    for (int i = threadIdx.x; i < 2048; i += 128) qks[i] = qkw[i];
    __syncthreads();
    if (s >= TT + 1) return;
    float acc[8];
#pragma unroll
    for (int hh = 0; hh < 8; ++hh) acc[hh] = qbw[hh];
    if (s == 0) {
        for (int i = 0; i < 256; ++i) {
            float v = cls[i];
#pragma unroll
            for (int hh = 0; hh < 8; ++hh) acc[hh] = fmaf(qks[hh * 256 + i], v, acc[hh]);
        }
    } else {
        const float* hb = h + (size_t)b * DD * TT + (s - 1);
        for (int i = 0; i < 256; ++i) {
            float v = hb[(size_t)i * TT];
#pragma unroll
            for (int hh = 0; hh < 8; ++hh) acc[hh] = fmaf(qks[hh * 256 + i], v, acc[hh]);
        }
    }
#pragma unroll
    for (int hh = 0; hh < 8; ++hh) sc[(size_t)(b * 8 + hh) * 1024 + s] = acc[hh];
}

__global__ __launch_bounds__(256) void k_softmax(const float* __restrict__ sc, float* __restrict__ att) {
    int row = blockIdx.x;
    const float* p = sc + (size_t)row * 1024;
    float* o = att + (size_t)row * 1024;
    __shared__ float red[256];
    float m = -3.4e38f;
    for (int s = threadIdx.x; s < TT + 1; s += 256) m = fmaxf(m, p[s]);
    red[threadIdx.x] = m; __syncthreads();
    for (int st = 128; st; st >>= 1) {
        if (threadIdx.x < st) red[threadIdx.x] = fmaxf(red[threadIdx.x], red[threadIdx.x + st]);
        __syncthreads();
    }
    m = red[0]; __syncthreads();
    float sum = 0.f;
    for (int s = threadIdx.x; s < TT + 1; s += 256) {
        float e = expf(p[s] - m);
        o[s] = e; sum += e;
    }
    red[threadIdx.x] = sum; __syncthreads();
    for (int st = 128; st; st >>= 1) {
        if (threadIdx.x < st) red[threadIdx.x] += red[threadIdx.x + st];
        __syncthreads();
    }
    float inv = 1.f / red[0];
    for (int s = threadIdx.x; s < TT + 1; s += 256) o[s] *= inv;
}

// ============ ctx stage 1: t-chunked partials ============
__global__ __launch_bounds__(256) void k_ctx1(const float* __restrict__ h,
                                              const float* __restrict__ att,
                                              float* __restrict__ ctx1) {
    __shared__ float as[8][256];
    int i0 = blockIdx.x * 32, tc = blockIdx.y, b = blockIdx.z;
    int tid = threadIdx.x;
    int sbase = tc * 250 + 1;
    for (int idx = tid; idx < 2048; idx += 256) {
        int hh = idx >> 8, u = idx & 255;
        as[hh][u] = (u < 250) ? att[(size_t)(b * 8 + hh) * 1024 + sbase + u] : 0.f;
    }
    __syncthreads();
    int w = tid >> 6, lane = tid & 63;
    for (int ii = 0; ii < 8; ++ii) {
        int i = i0 + w * 8 + ii;
        const float* hb = h + ((size_t)(b * DD + i)) * TT + tc * 250;
        float acc[8];
#pragma unroll
        for (int hh = 0; hh < 8; ++hh) acc[hh] = 0.f;
        for (int u = lane; u < 250; u += 64) {
            float v = hb[u];
#pragma unroll
            for (int hh = 0; hh < 8; ++hh) acc[hh] = fmaf(as[hh][u], v, acc[hh]);
        }
#pragma unroll
        for (int off = 32; off; off >>= 1)
#pragma unroll
            for (int hh = 0; hh < 8; ++hh) acc[hh] += __shfl_down(acc[hh], off);
        if (lane == 0) {
#pragma unroll
            for (int hh = 0; hh < 8; ++hh)
                ctx1[(((size_t)tc * BB + b) * 8 + hh) * DD + i] = acc[hh];
        }
    }
}

// ============ head: reduce ctx partials + cls term, then MLP ============
__global__ __launch_bounds__(256) void k_head(const float* __restrict__ ctx1,
                                              const float* __restrict__ att,
                                              const float* __restrict__ cls,
                                              const float* __restrict__ inw,
                                              const float* __restrict__ inb, const float* __restrict__ outw,
                                              const float* __restrict__ outb, const float* __restrict__ w1,
                                              const float* __restrict__ b1, const float* __restrict__ w2,
                                              const float* __restrict__ b2, float* __restrict__ out) {
    int b = blockIdx.x;
    __shared__ float cs[2048], ao[256], po[256], hid[128];
    int j = threadIdx.x;
    {
        float cv = cls[j];
#pragma unroll
        for (int hh = 0; hh < 8; ++hh) {
            float a = att[(size_t)(b * 8 + hh) * 1024] * cv;
#pragma unroll
            for (int tc = 0; tc < 4; ++tc)
                a += ctx1[(((size_t)tc * BB + b) * 8 + hh) * DD + j];
            cs[hh * 256 + j] = a;
        }
    }
    __syncthreads();
    {
        int hh = j >> 5;
        float a = inb[2 * DD + j];
        const float* wv = inw + (size_t)(2 * DD + j) * DD;
        for (int i = 0; i < 256; ++i) a = fmaf(wv[i], cs[hh * 256 + i], a);
        ao[j] = a;
    }
    __syncthreads();
    {
        float a = outb[j];
        for (int i = 0; i < 256; ++i) a = fmaf(outw[j * DD + i], ao[i], a);
        po[j] = a;
    }
    __syncthreads();
    if (j < 128) {
        float a = b1[j];
        for (int i = 0; i < 256; ++i) a = fmaf(w1[j * 256 + i], po[i], a);
        hid[j] = fmaxf(a, 0.f);
    }
    __syncthreads();
    if (j == 0) {
        float a = b2[0];
        for (int i = 0; i < 128; ++i) a = fmaf(w2[i], hid[i], a);
        out[b] = a;
    }
}

extern "C" void kernel_launch(void* const* d_in, const int* in_sizes, int n_in,
                              void* d_out, int out_size, void* d_ws, size_t ws_size,
                              hipStream_t stream) {
    (void)in_sizes; (void)n_in; (void)out_size; (void)ws_size;
    const float* x        = (const float*)d_in[0];
    const float* w_in     = (const float*)d_in[1];
    const float* b_in     = (const float*)d_in[2];
    const float* ln_in_g  = (const float*)d_in[3];
    const float* ln_in_b  = (const float*)d_in[4];
    const float* s4B      = (const float*)d_in[5];
    const float* s4C      = (const float*)d_in[6];
    const float* s4logdt  = (const float*)d_in[7];
    const float* s4D      = (const float*)d_in[8];
    const float* ln_g     = (const float*)d_in[9];
    const float* ln_b     = (const float*)d_in[10];
    const float* cls      = (const float*)d_in[11];
    const float* mha_in_w = (const float*)d_in[12];
    const float* mha_in_b = (const float*)d_in[13];
    const float* mha_out_w= (const float*)d_in[14];
    const float* mha_out_b= (const float*)d_in[15];
    const float* head_w1  = (const float*)d_in[16];
    const float* head_b1  = (const float*)d_in[17];
    const float* head_w2  = (const float*)d_in[18];
    const float* head_b2  = (const float*)d_in[19];

    float* ws   = (float*)d_ws;
    float* h    = ws + OFF_H;
    float* kker = ws + OFF_K;
    float* invn = ws + OFF_INV;
    float* P  = h;                 // 33 * 4096
    float* Q  = h + 540672;        // 32 * 4096
    float* Lb = h + 1064960;
    float* Rb = h + 3162112;
    float* qkb  = ws + OFF_MHA;
    float* qbb  = qkb + 2048;
    float* scb  = qbb + 16;        // reused: whi/wlo (pre-embed), ctx1 (post-softmax)
    float* attb = scb + 262144;
    unsigned short* whi = (unsigned short*)scb;
    unsigned short* wlo = whi + 256 * 136;
    float* ctx1b = scb;

    k_build_ad<<<dim3(257), dim3(256), 0, stream>>>(s4logdt, P, w_in, whi, wlo);
    k_powers<<<dim3(62), dim3(256), 0, stream>>>(P, Q);
    k_lr<<<dim3(NLY * 64), dim3(256), 0, stream>>>(P, Q, s4B, s4C, Lb, Rb);
    k_kker<<<dim3(NLY * 256), dim3(256), 0, stream>>>(Lb, Rb, kker);

    k_embed_mfma<<<dim3(16, BB), dim3(512), 0, stream>>>(x, whi, wlo, w_in, b_in,
                                                         ln_in_g, ln_in_b, h, invn);

    for (int l = 0; l < NLY; ++l) {
        k_conv32<<<dim3(DD), dim3(512), 0, stream>>>(h, kker, invn, s4D, l);
        k_ln<<<dim3(16, BB), dim3(256), 0, stream>>>(h, ln_g + l * DD, ln_b + l * DD, h, invn);
    }

    k_qprep<<<dim3(1), dim3(256), 0, stream>>>(cls, mha_in_w, mha_in_b, qkb, qbb);
    k_scores<<<dim3(8, BB), dim3(128), 0, stream>>>(h, cls, qkb, qbb, scb);
    k_softmax<<<dim3(256), dim3(256), 0, stream>>>(scb, attb);
    k_ctx1<<<dim3(8, 4, BB), dim3(256), 0, stream>>>(h, attb, ctx1b);
    k_head<<<dim3(BB), dim3(256), 0, stream>>>(ctx1b, attb, cls, mha_in_w, mha_in_b,
                                               mha_out_w, mha_out_b,
                                               head_w1, head_b1, head_w2, head_b2, (float*)d_out);
}

// Round 8
// 517.399 us; speedup vs baseline: 1.1344x; 1.0377x over previous
//
#include <hip/hip_runtime.h>

#define BB 32
#define CC 129
#define TT 1000
#define DD 256
#define NN 64
#define NLY 4

// ---------------- workspace layout (floats) ----------------
#define OFF_H    0
#define OFF_K    8192000
#define OFF_INV  9232384
#define OFF_MHA  9264384

typedef __attribute__((ext_vector_type(8))) short bf16x8;
typedef __attribute__((ext_vector_type(8))) _Float16 f16x8;
typedef __attribute__((ext_vector_type(4))) float f32x4;
typedef __attribute__((ext_vector_type(16))) float f32x16;

__device__ __forceinline__ unsigned short f2bf(float x) {
    unsigned int u = __float_as_uint(x);
    unsigned int r = (u + 0x7FFF + ((u >> 16) & 1)) >> 16;
    return (unsigned short)r;
}
__device__ __forceinline__ float bf2f(unsigned short b) {
    return __uint_as_float(((unsigned int)b) << 16);
}
__device__ __forceinline__ unsigned short f2h(float x) {
    _Float16 v = (_Float16)x;
    return *(unsigned short*)&v;
}
__device__ __forceinline__ float h2f(unsigned short b) {
    _Float16 v = *(_Float16*)&b;
    return (float)v;
}

// ============ Ad build (block 0) + w_in split-bf16 prep (blocks 1..256) ============
// v5: closed-form Sherman-Morrison + Newton polish. HW-verified (R4, R7; absmax 0).
#define BST 68
__global__ __launch_bounds__(256, 1) void k_build_ad(const float* __restrict__ logdt,
                                                     float* __restrict__ P,
                                                     const float* __restrict__ w_in,
                                                     unsigned short* __restrict__ whi,
                                                     unsigned short* __restrict__ wlo) {
    int tid = threadIdx.x;
    if (blockIdx.x != 0) {
        int d = blockIdx.x - 1;      // 0..255
        int c = tid;
        if (c < 136) {
            float v = (c < CC) ? w_in[d * CC + c] : 0.f;
            unsigned short h = f2bf(v);
            whi[d * 136 + c] = h;
            wlo[d * 136 + c] = f2bf(v - bf2f(h));
        }
        return;
    }
    __shared__ __align__(16) float Ms[64 * BST];
    __shared__ __align__(16) float Vs[64 * BST];
    __shared__ __align__(16) float Ws[64 * BST];
    float dt = expf(logdt[0]);
    dt = fminf(fmaxf(dt, 1e-4f), 0.1f);
    float hh = dt * 0.5f;
    int w = tid >> 6, r = tid & 63;
    {
        float Pr = sqrtf(1.f + 2.f * (float)r);
#pragma unroll
        for (int jj = 0; jj < 16; ++jj) {
            int j = w * 16 + jj;
            float av;
            if (r == j) av = -((float)r + 0.5f);
            else { float m = Pr * sqrtf(1.f + 2.f * (float)j); av = (r > j) ? -m : m; }
            Ms[r * BST + j] = ((r == j) ? 1.f : 0.f) - hh * av;
        }
    }
    if (tid < 64) {
        int lane = tid;
        float x[64], u[64];
        float s = 0.f, su = 0.f;
#pragma unroll
        for (int i = 0; i < 64; ++i) {
            const float Pi = sqrtf(2.f * (float)i + 1.f);
            float Lii = fmaf(3.f * ((float)i + 0.5f), hh, 1.f);
            float rinv = 1.f / Lii;
            float c = 2.f * hh * Pi;
            float del = (lane == i) ? 1.f : 0.f;
            x[i] = (del - c * s) * rinv;
            s = fmaf(Pi, x[i], s);
            u[i] = (Pi - c * su) * rinv;
            su = fmaf(Pi, u[i], su);
        }
        float beta = hh / (1.f - hh * su);
        float bv = beta * s;
#pragma unroll
        for (int i = 0; i < 64; ++i)
            Vs[i * BST + lane] = fmaf(bv, u[i], x[i]);
    }
    __syncthreads();
    // ---- Newton refine, step A: W = 2I - M*V ----
    {
        int tr = (tid >> 4) << 2, tc = (tid & 15) << 2;
        float acc[4][4];
#pragma unroll
        for (int u = 0; u < 4; ++u)
#pragma unroll
            for (int v = 0; v < 4; ++v) acc[u][v] = 0.f;
        for (int k0 = 0; k0 < 64; k0 += 4) {
            f32x4 av[4], bv[4];
#pragma unroll
            for (int u = 0; u < 4; ++u) av[u] = *(const f32x4*)&Ms[(tr + u) * BST + k0];
#pragma unroll
            for (int kk = 0; kk < 4; ++kk) bv[kk] = *(const f32x4*)&Vs[(k0 + kk) * BST + tc];
#pragma unroll
            for (int u = 0; u < 4; ++u)
#pragma unroll
                for (int kk = 0; kk < 4; ++kk)
#pragma unroll
                    for (int v = 0; v < 4; ++v)
                        acc[u][v] = fmaf(av[u][kk], bv[kk][v], acc[u][v]);
        }
        __syncthreads();
#pragma unroll
        for (int u = 0; u < 4; ++u)
#pragma unroll
            for (int v = 0; v < 4; ++v)
                Ws[(tr + u) * BST + tc + v] =
                    (((tr + u) == (tc + v)) ? 2.f : 0.f) - acc[u][v];
    }
    __syncthreads();
    // ---- Newton refine, step B: Ad = 2*(V*W) - I ; also P[0] = I ----
    {
        int tr = (tid >> 4) << 2, tc = (tid & 15) << 2;
        float acc[4][4];
#pragma unroll
        for (int u = 0; u < 4; ++u)
#pragma unroll
            for (int v = 0; v < 4; ++v) acc[u][v] = 0.f;
        for (int k0 = 0; k0 < 64; k0 += 4) {
            f32x4 av[4], bv[4];
#pragma unroll
            for (int u = 0; u < 4; ++u) av[u] = *(const f32x4*)&Vs[(tr + u) * BST + k0];
#pragma unroll
            for (int kk = 0; kk < 4; ++kk) bv[kk] = *(const f32x4*)&Ws[(k0 + kk) * BST + tc];
#pragma unroll
            for (int u = 0; u < 4; ++u)
#pragma unroll
                for (int kk = 0; kk < 4; ++kk)
#pragma unroll
                    for (int v = 0; v < 4; ++v)
                        acc[u][v] = fmaf(av[u][kk], bv[kk][v], acc[u][v]);
        }
#pragma unroll
        for (int u = 0; u < 4; ++u)
#pragma unroll
            for (int v = 0; v < 4; ++v) {
                int rr = tr + u, cc = tc + v;
                float eye = (rr == cc) ? 1.f : 0.f;
                P[rr * 64 + cc] = eye;
                P[4096 + rr * 64 + cc] = 2.f * acc[u][v] - eye;
            }
    }
}

// ============ single-launch power table: P[j]=Ad^j (j=2..31), Q[i]=Ad^(32i) (i=0..31) ====
#define PLDA 68
__device__ __forceinline__ void mm64x(float* D, const float* A, const float* B) {
    int tr = (threadIdx.x >> 4) << 2, tc = (threadIdx.x & 15) << 2;
    float acc[4][4];
#pragma unroll
    for (int u = 0; u < 4; ++u)
#pragma unroll
        for (int v = 0; v < 4; ++v) acc[u][v] = 0.f;
#pragma unroll 2
    for (int k0 = 0; k0 < 64; k0 += 4) {
        f32x4 av[4], bv[4];
#pragma unroll
        for (int u = 0; u < 4; ++u) av[u] = *(const f32x4*)&A[(tr + u) * PLDA + k0];
#pragma unroll
        for (int kk = 0; kk < 4; ++kk) bv[kk] = *(const f32x4*)&B[(k0 + kk) * PLDA + tc];
#pragma unroll
        for (int u = 0; u < 4; ++u)
#pragma unroll
            for (int kk = 0; kk < 4; ++kk)
#pragma unroll
                for (int v = 0; v < 4; ++v)
                    acc[u][v] = fmaf(av[u][kk], bv[kk][v], acc[u][v]);
    }
    __syncthreads();
#pragma unroll
    for (int u = 0; u < 4; ++u)
#pragma unroll
        for (int v = 0; v < 4; ++v) D[(tr + u) * PLDA + tc + v] = acc[u][v];
    __syncthreads();
}

__device__ float* powm(float* U, float* V, const float* base, int e) {
    for (int i = threadIdx.x; i < 4096; i += 256)
        U[(i >> 6) * PLDA + (i & 63)] = base[(i >> 6) * PLDA + (i & 63)];
    __syncthreads();
    float* X = U; float* Y = V;
    for (int bit = 30 - __builtin_clz(e); bit >= 0; --bit) {
        mm64x(Y, X, X); { float* t = X; X = Y; Y = t; }
        if ((e >> bit) & 1) { mm64x(Y, X, base); float* t = X; X = Y; Y = t; }
    }
    return X;
}

__global__ __launch_bounds__(256) void k_powers(float* __restrict__ P, float* __restrict__ Q) {
    __shared__ __align__(16) float AdS[64 * PLDA];
    __shared__ __align__(16) float BaseS[64 * PLDA];
    __shared__ __align__(16) float Ub[64 * PLDA];
    __shared__ __align__(16) float Vb[64 * PLDA];
    int tid = threadIdx.x, bid = blockIdx.x;
    if (bid == 61) {   // Q[0] = I
        for (int i = tid; i < 4096; i += 256) Q[i] = ((i >> 6) == (i & 63)) ? 1.f : 0.f;
        return;
    }
    const float* Ad = P + 4096;
    for (int i = tid; i < 4096; i += 256) AdS[(i >> 6) * PLDA + (i & 63)] = Ad[i];
    __syncthreads();
    float* res;
    float* out;
    if (bid < 30) {                    // P[2+bid] = Ad^(2+bid)
        res = powm(Ub, Vb, AdS, bid + 2);
        out = P + (size_t)(bid + 2) * 4096;
    } else {                           // Q[i] = (Ad^32)^i, i = bid-29 in 1..31
        int iq = bid - 29;
        float* b32 = powm(Ub, Vb, AdS, 32);
        for (int i = tid; i < 4096; i += 256)
            BaseS[(i >> 6) * PLDA + (i & 63)] = b32[(i >> 6) * PLDA + (i & 63)];
        __syncthreads();
        res = powm(Ub, Vb, BaseS, iq);
        out = Q + (size_t)iq * 4096;
    }
    for (int i = tid; i < 4096; i += 256) out[i] = res[(i >> 6) * PLDA + (i & 63)];
}

// ============ L / R ============
__global__ __launch_bounds__(256) void k_lr(const float* __restrict__ P, const float* __restrict__ Q,
                                            const float* __restrict__ s4B, const float* __restrict__ s4C,
                                            float* __restrict__ L, float* __restrict__ R) {
    __shared__ float Ms[4096];
    int l = blockIdx.x >> 6, rem = blockIdx.x & 63, which = rem >> 5, idx = rem & 31;
    const float* M = which ? (P + (size_t)idx * 4096)
                           : (Q + (size_t)idx * 4096);
    for (int i = threadIdx.x; i < 4096; i += 256) Ms[i] = M[i];
    __syncthreads();
    int d = threadIdx.x;
    if (which == 0) {
        float* dst = L + (((size_t)(l * DD + d) * 32 + idx) * 64);
        for (int jc = 0; jc < 8; ++jc) {
            float acc[8];
#pragma unroll
            for (int u = 0; u < 8; ++u) acc[u] = 0.f;
            for (int i = 0; i < 64; ++i) {
                float bv = s4B[(l * NN + i) * DD + d];
#pragma unroll
                for (int u = 0; u < 8; ++u)
                    acc[u] = fmaf(bv, Ms[i * 64 + jc * 8 + u], acc[u]);
            }
#pragma unroll
            for (int u = 0; u < 8; ++u) dst[jc * 8 + u] = acc[u];
        }
    } else {
        float* dst = R + (((size_t)(l * DD + d) * 32 + idx) * 64);
        const float* Cp = s4C + (size_t)(l * DD + d) * NN;
        for (int ic = 0; ic < 8; ++ic) {
            float acc[8];
#pragma unroll
            for (int u = 0; u < 8; ++u) acc[u] = 0.f;
            for (int j = 0; j < 64; ++j) {
                float cv = Cp[j];
#pragma unroll
                for (int u = 0; u < 8; ++u)
                    acc[u] = fmaf(Ms[(ic * 8 + u) * 64 + j], cv, acc[u]);
            }
#pragma unroll
            for (int u = 0; u < 8; ++u) dst[ic * 8 + u] = acc[u];
        }
    }
}

// ============ kernel assembly ============
__global__ __launch_bounds__(256) void k_kker(const float* __restrict__ L, const float* __restrict__ R,
                                              float* __restrict__ kk) {
    __shared__ float Ls[32 * 65], Rs[32 * 65];
    int l = blockIdx.x >> 8, d = blockIdx.x & 255;
    const float* Lp = L + ((size_t)(l * DD + d) * 32) * 64;
    const float* Rp = R + ((size_t)(l * DD + d) * 32) * 64;
    for (int i = threadIdx.x; i < 2048; i += 256) {
        int row = i >> 6, col = i & 63;
        Ls[row * 65 + col] = Lp[i];
        Rs[row * 65 + col] = Rp[i];
    }
    __syncthreads();
    for (int t = threadIdx.x; t < TT; t += 256) {
        int kq = t >> 5, r = t & 31;
        const float* lr = &Ls[kq * 65];
        const float* rr = &Rs[r * 65];
        float a = 0.f;
#pragma unroll 8
        for (int m = 0; m < 64; ++m) a = fmaf(lr[m], rr[m], a);
        kk[(size_t)(l * DD + d) * TT + t] = a * expf(-0.01f * (float)t);
    }
}

// ============ MFMA embed + fused LayerNorm + pos-encoding + invn ============
__global__ __launch_bounds__(512, 4) void k_embed_mfma(const float* __restrict__ x,
                                                    const unsigned short* __restrict__ whi,
                                                    const unsigned short* __restrict__ wlo,
                                                    const float* __restrict__ w_in,
                                                    const float* __restrict__ b_in,
                                                    const float* __restrict__ lng,
                                                    const float* __restrict__ lnb,
                                                    float* __restrict__ h,
                                                    float* __restrict__ invn) {
    __shared__ unsigned short xs_h[64 * 130], xs_l[64 * 130];
    __shared__ float xlasts[64], w128s[256], biass[256], gs[256], bs[256];
    __shared__ float ps[64][8], ps2[64][8];
    __shared__ float mstat[64], rstat[64];
    int b = blockIdx.y, t0 = blockIdx.x * 64;
    int tid = threadIdx.x;
    for (int i = tid; i < CC * 64; i += 512) {
        int c = i >> 6, tl = i & 63;
        int t = t0 + tl;
        float v = (t < TT) ? x[(size_t)(b * CC + c) * TT + t] : 0.f;
        if (c == 128) {
            xlasts[tl] = v;
        } else {
            unsigned short hh = f2bf(v);
            xs_h[tl * 130 + c] = hh;
            xs_l[tl * 130 + c] = f2bf(v - bf2f(hh));
        }
    }
    if (tid < 256) {
        w128s[tid] = w_in[tid * CC + 128];
        biass[tid] = b_in[tid];
        gs[tid] = lng[tid];
        bs[tid] = lnb[tid];
    }
    __syncthreads();
    int wave = tid >> 6, lane = tid & 63;
    int tn = lane & 15, q = lane >> 4;
    int d0w = wave * 32;
    f32x4 acc[4][2];
#pragma unroll
    for (int nt = 0; nt < 4; ++nt)
#pragma unroll
        for (int mt = 0; mt < 2; ++mt) acc[nt][mt] = (f32x4){0.f, 0.f, 0.f, 0.f};
#pragma unroll
    for (int kc = 0; kc < 4; ++kc) {
        int c0 = kc * 32;
        bf16x8 Ah[2], Al[2];
#pragma unroll
        for (int mt = 0; mt < 2; ++mt) {
            int base = (d0w + mt * 16 + tn) * 136 + c0 + 8 * q;
            Ah[mt] = *(const bf16x8*)&whi[base];
            Al[mt] = *(const bf16x8*)&wlo[base];
        }
#pragma unroll
        for (int nt = 0; nt < 4; ++nt) {
            const unsigned int* ph = (const unsigned int*)&xs_h[(nt * 16 + tn) * 130 + c0 + 8 * q];
            const unsigned int* pl = (const unsigned int*)&xs_l[(nt * 16 + tn) * 130 + c0 + 8 * q];
            union { bf16x8 v; unsigned int u[4]; } Bh, Bl;
            Bh.u[0] = ph[0]; Bh.u[1] = ph[1]; Bh.u[2] = ph[2]; Bh.u[3] = ph[3];
            Bl.u[0] = pl[0]; Bl.u[1] = pl[1]; Bl.u[2] = pl[2]; Bl.u[3] = pl[3];
#pragma unroll
            for (int mt = 0; mt < 2; ++mt) {
                acc[nt][mt] = __builtin_amdgcn_mfma_f32_16x16x32_bf16(Al[mt], Bh.v, acc[nt][mt], 0, 0, 0);
                acc[nt][mt] = __builtin_amdgcn_mfma_f32_16x16x32_bf16(Ah[mt], Bl.v, acc[nt][mt], 0, 0, 0);
                acc[nt][mt] = __builtin_amdgcn_mfma_f32_16x16x32_bf16(Ah[mt], Bh.v, acc[nt][mt], 0, 0, 0);
            }
        }
    }
#pragma unroll
    for (int nt = 0; nt < 4; ++nt) {
        float xl = xlasts[nt * 16 + tn];
        float s = 0.f, s2 = 0.f;
#pragma unroll
        for (int mt = 0; mt < 2; ++mt) {
#pragma unroll
            for (int r = 0; r < 4; ++r) {
                int d = d0w + mt * 16 + 4 * q + r;
                float v = acc[nt][mt][r] + biass[d] + w128s[d] * xl;
                acc[nt][mt][r] = v;
                s += v; s2 = fmaf(v, v, s2);
            }
        }
        s += __shfl_xor(s, 16); s += __shfl_xor(s, 32);
        s2 += __shfl_xor(s2, 16); s2 += __shfl_xor(s2, 32);
        if (q == 0) { ps[nt * 16 + tn][wave] = s; ps2[nt * 16 + tn][wave] = s2; }
    }
    __syncthreads();
    if (tid < 64) {
        float s = 0.f, s2 = 0.f;
#pragma unroll
        for (int k = 0; k < 8; ++k) { s += ps[tid][k]; s2 += ps2[tid][k]; }
        float mean = s * (1.f / 256.f);
        float ex2 = s2 * (1.f / 256.f);
        mstat[tid] = mean;
        rstat[tid] = 1.f / sqrtf(ex2 - mean * mean + 1e-5f);
    }
    __syncthreads();
    float sq[4] = {0.f, 0.f, 0.f, 0.f};
#pragma unroll
    for (int mt = 0; mt < 2; ++mt) {
#pragma unroll
        for (int r = 0; r < 4; ++r) {
            int d = d0w + mt * 16 + 4 * q + r;
            float gd = gs[d], bd = bs[d];
            float freq = expf((float)(d & ~1) * (-9.210340371976184f / 256.f));
            int odd = d & 1;
#pragma unroll
            for (int nt = 0; nt < 4; ++nt) {
                int tl = nt * 16 + tn;
                int t = t0 + tl;
                float o = (acc[nt][mt][r] - mstat[tl]) * rstat[tl] * gd + bd;
                float ang = (float)t * freq;
                o += odd ? cosf(ang) : sinf(ang);
                if (t < TT) h[((size_t)(b * DD + d)) * TT + t] = o;
                sq[nt] = fmaf(o, o, sq[nt]);
            }
        }
    }
#pragma unroll
    for (int nt = 0; nt < 4; ++nt) {
        float s = sq[nt];
        s += __shfl_xor(s, 16); s += __shfl_xor(s, 32);
        if (q == 0) ps[nt * 16 + tn][wave] = s;
    }
    __syncthreads();
    if (tid < 64) {
        int t = t0 + tid;
        if (t < TT) {
            float s = 0.f;
#pragma unroll
            for (int k = 0; k < 8; ++k) s += ps[tid][k];
            invn[b * TT + t] = 1.f / (sqrtf(s) + 1e-8f);
        }
    }
}

// ============ LayerNorm (in-place), single-pass ============
// v1 form (HW-verified): compiler re-read of `in` is L2-hot and nearly free.
__global__ __launch_bounds__(256) void k_ln(const float* __restrict__ in, const float* __restrict__ g,
                                            const float* __restrict__ bia, float* __restrict__ out,
                                            float* __restrict__ invn) {
    int b = blockIdx.y, t0 = blockIdx.x * 64;
    int w = threadIdx.x >> 6, lane = threadIdx.x & 63;
    int t = t0 + lane;
    __shared__ float ps[4][64], ps2[4][64];
    float v[64];
    float s = 0.f, s2 = 0.f;
    bool ok = t < TT;
#pragma unroll
    for (int k = 0; k < 64; ++k) {
        float x = ok ? in[(size_t)(b * DD + (w + 4 * k)) * TT + t] : 0.f;
        v[k] = x;
        s += x; s2 = fmaf(x, x, s2);
    }
    ps[w][lane] = s; ps2[w][lane] = s2;
    __syncthreads();
    float mean = (ps[0][lane] + ps[1][lane] + ps[2][lane] + ps[3][lane]) * (1.f / 256.f);
    float ex2  = (ps2[0][lane] + ps2[1][lane] + ps2[2][lane] + ps2[3][lane]) * (1.f / 256.f);
    float rstd = 1.f / sqrtf(ex2 - mean * mean + 1e-5f);
    float sq = 0.f;
    if (ok) {
#pragma unroll
        for (int k = 0; k < 64; ++k) {
            int d = w + 4 * k;
            float o = (v[k] - mean) * rstd * g[d] + bia[d];
            out[(size_t)(b * DD + d) * TT + t] = o;
            sq = fmaf(o, o, sq);
        }
    }
    __syncthreads();
    ps[w][lane] = sq;
    __syncthreads();
    if (w == 0 && ok) {
        float tot = ps[0][lane] + ps[1][lane] + ps[2][lane] + ps[3][lane];
        invn[b * TT + t] = 1.f / (sqrtf(tot) + 1e-8f);
    }
}

__device__ __forceinline__ float gelu_exact(float y) {
    return 0.5f * y * (1.f + erff(y * 0.7071067811865476f));
}

// ============ MFMA conv v3: safe 16-batch split, grid (DD, 2) ============
// v1 was 1 block/CU (25% occ). v3 keeps v1's loop structure EXACTLY (same pass loop,
// same wave-uniform u0>=0 guard, same B path) and only narrows batches 32->16:
// A-row index nn -> nn&15 (always in-bounds, no conditionals). MFMA rows 16-31
// compute duplicates of rows 0-15 (D rows depend only on own A row -> written rows
// bitwise-identical to v1); epilogue skips brow>=16 (folds to compile-time r<8).
// LDS 37KB, grid 512 -> 2 blocks/CU, 16 waves/CU. NO divergent operand zeroing
// (v2's pattern, correlated with container failures).
#define XS2 1032
__global__ __launch_bounds__(512) void k_conv32(float* __restrict__ h, const float* __restrict__ kk,
                                                const float* __restrict__ invn,
                                                const float* __restrict__ s4D, int layer) {
    __shared__ unsigned short Xs[16 * XS2];
    __shared__ unsigned int pks[1056];
    int d = blockIdx.x;
    int bbase = blockIdx.y * 16;
    int tid = threadIdx.x;
    const float* krow = kk + (size_t)(layer * DD + d) * TT;
    for (int mm = tid; mm < 1056; mm += 512) {
        int m = mm - 32;
        float klo = (m >= 0 && m < TT) ? krow[m] : 0.f;
        float kpr = (m >= 1 && m <= TT) ? krow[m - 1] : 0.f;
        pks[mm] = (unsigned int)f2h(klo) | ((unsigned int)f2h(kpr) << 16);
    }
    for (int ii = tid; ii < 16 * 512; ii += 512) {
        int bb = ii >> 9;                       // 0..15 local batch
        int tp = (ii & 511) * 2;
        const float* hrow = h + ((size_t)(bbase + bb) * DD + d) * TT;
        const float* ivr = invn + (size_t)(bbase + bb) * TT;
        float v0 = (tp < TT) ? hrow[tp] * ivr[tp] : 0.f;
        float v1 = (tp + 1 < TT) ? hrow[tp + 1] * ivr[tp + 1] : 0.f;
        ((unsigned int*)Xs)[(bb * XS2 + tp) >> 1] = (unsigned int)f2h(v0) | ((unsigned int)f2h(v1) << 16);
    }
    __syncthreads();
    float gate = 1.f / (1.f + expf(-s4D[layer * DD + d]));
    int wave = tid >> 6, lane = tid & 63;
    int nn = lane & 31, kq8 = (lane >> 5) << 3;
    int bp = nn & 15;                           // A-row batch (rows 16-31 duplicate 0-15)
    for (int pass = 0; pass < 2; ++pass) {
        int G = pass ? (15 - wave) : wave;
        int jlo = 2 * G;
        f32x16 acc[2];
#pragma unroll
        for (int m = 0; m < 2; ++m)
#pragma unroll
            for (int r = 0; r < 16; ++r) acc[m][r] = 0.f;
        for (int D = 32 * jlo + 32; D >= -16; D -= 16) {
            int S32 = D + nn - kq8 + 32;
            union { f16x8 v; unsigned int u[4]; } bh;
            bh.u[0] = pks[S32];
            bh.u[1] = pks[S32 - 2];
            bh.u[2] = pks[S32 - 4];
            bh.u[3] = pks[S32 - 6];
#pragma unroll
            for (int m = 0; m < 2; ++m) {
                int u0 = (jlo + m) * 32 - D;
                if (u0 >= 0) {
                    const f16x8 ah = *(const f16x8*)&Xs[bp * XS2 + u0 + kq8];
                    acc[m] = __builtin_amdgcn_mfma_f32_32x32x16_f16(ah, bh.v, acc[m], 0, 0, 0);
                }
            }
        }
#pragma unroll
        for (int m = 0; m < 2; ++m) {
            int t = (jlo + m) * 32 + nn;
            if (t < TT) {
#pragma unroll
                for (int r = 0; r < 16; ++r) {
                    int brow = (r & 3) + 8 * (r >> 2) + 4 * (lane >> 5);
                    if (brow < 16) {            // rows 16-31 are discarded duplicates
                        size_t ix = ((size_t)(bbase + brow) * DD + d) * TT + t;
                        float y = acc[m][r];
                        float xn = h2f(Xs[brow * XS2 + t]);
                        float ho = h[ix];       // L2-hot re-read (exact residual)
                        h[ix] = gelu_exact(y + xn * gate) + 1.1f * ho;
                    }
                }
            }
        }
    }
}

// ============ MHA pooling ============
__global__ __launch_bounds__(256) void k_qprep(const float* __restrict__ cls, const float* __restrict__ inw,
                                               const float* __restrict__ inb, float* __restrict__ qk,
                                               float* __restrict__ qb) {
    __shared__ float Qv[256];
    int j = threadIdx.x;
    float a = inb[j];
    for (int i = 0; i < 256; ++i) a = fmaf(inw[j * DD + i], cls[i], a);
    Qv[j] = a;
    __syncthreads();
    const float scale = 0.17677669529663687f; // 1/sqrt(32)
    for (int idx = threadIdx.x; idx < 8 * 256; idx += 256) {
        int hh = idx >> 8, i = idx & 255;
        float s = 0.f;
        for (int jj = 0; jj < 32; ++jj)
            s = fmaf(Qv[hh * 32 + jj], inw[(DD + hh * 32 + jj) * DD + i], s);
        qk[idx] = s * scale;
    }
    if (threadIdx.x < 8) {
        int hh = threadIdx.x;
        float s = 0.f;
        for (int jj = 0; jj < 32; ++jj)
            s = fmaf(Qv[hh * 32 + jj], inb[DD + hh * 32 + jj], s);
        qb[hh] = s * scale;
    }
}

__global__ __launch_bounds__(128) void k_scores(const float* __restrict__ h, const float* __restrict__ cls,
                                                const float* __restrict__ qkw, const float* __restrict__ qbw,
                                                float* __restrict__ sc) {
    __shared__ float qks[8 * 256];
    int b = blockIdx.y;
    int s = blockIdx.x * 128 + threadIdx.x;
    for (int i = threadIdx.x; i < 2048; i += 128) qks[i] = qkw[i];
    __syncthreads();
    if (s >= TT + 1) return;
    float acc[8];
#pragma unroll
    for (int hh = 0; hh < 8; ++hh) acc[hh] = qbw[hh];
    if (s == 0) {
        for (int i = 0; i < 256; ++i) {
            float v = cls[i];
#pragma unroll
            for (int hh = 0; hh < 8; ++hh) acc[hh] = fmaf(qks[hh * 256 + i], v, acc[hh]);
        }
    } else {
        const float* hb = h + (size_t)b * DD * TT + (s - 1);
        for (int i = 0; i < 256; ++i) {
            float v = hb[(size_t)i * TT];
#pragma unroll
            for (int hh = 0; hh < 8; ++hh) acc[hh] = fmaf(qks[hh * 256 + i], v, acc[hh]);
        }
    }
#pragma unroll
    for (int hh = 0; hh < 8; ++hh) sc[(size_t)(b * 8 + hh) * 1024 + s] = acc[hh];
}

__global__ __launch_bounds__(256) void k_softmax(const float* __restrict__ sc, float* __restrict__ att) {
    int row = blockIdx.x;
    const float* p = sc + (size_t)row * 1024;
    float* o = att + (size_t)row * 1024;
    __shared__ float red[256];
    float m = -3.4e38f;
    for (int s = threadIdx.x; s < TT + 1; s += 256) m = fmaxf(m, p[s]);
    red[threadIdx.x] = m; __syncthreads();
    for (int st = 128; st; st >>= 1) {
        if (threadIdx.x < st) red[threadIdx.x] = fmaxf(red[threadIdx.x], red[threadIdx.x + st]);
        __syncthreads();
    }
    m = red[0]; __syncthreads();
    float sum = 0.f;
    for (int s = threadIdx.x; s < TT + 1; s += 256) {
        float e = expf(p[s] - m);
        o[s] = e; sum += e;
    }
    red[threadIdx.x] = sum; __syncthreads();
    for (int st = 128; st; st >>= 1) {
        if (threadIdx.x < st) red[threadIdx.x] += red[threadIdx.x + st];
        __syncthreads();
    }
    float inv = 1.f / red[0];
    for (int s = threadIdx.x; s < TT + 1; s += 256) o[s] *= inv;
}

// ============ ctx stage 1: t-chunked partials ============
__global__ __launch_bounds__(256) void k_ctx1(const float* __restrict__ h,
                                              const float* __restrict__ att,
                                              float* __restrict__ ctx1) {
    __shared__ float as[8][256];
    int i0 = blockIdx.x * 32, tc = blockIdx.y, b = blockIdx.z;
    int tid = threadIdx.x;
    int sbase = tc * 250 + 1;
    for (int idx = tid; idx < 2048; idx += 256) {
        int hh = idx >> 8, u = idx & 255;
        as[hh][u] = (u < 250) ? att[(size_t)(b * 8 + hh) * 1024 + sbase + u] : 0.f;
    }
    __syncthreads();
    int w = tid >> 6, lane = tid & 63;
    for (int ii = 0; ii < 8; ++ii) {
        int i = i0 + w * 8 + ii;
        const float* hb = h + ((size_t)(b * DD + i)) * TT + tc * 250;
        float acc[8];
#pragma unroll
        for (int hh = 0; hh < 8; ++hh) acc[hh] = 0.f;
        for (int u = lane; u < 250; u += 64) {
            float v = hb[u];
#pragma unroll
            for (int hh = 0; hh < 8; ++hh) acc[hh] = fmaf(as[hh][u], v, acc[hh]);
        }
#pragma unroll
        for (int off = 32; off; off >>= 1)
#pragma unroll
            for (int hh = 0; hh < 8; ++hh) acc[hh] += __shfl_down(acc[hh], off);
        if (lane == 0) {
#pragma unroll
            for (int hh = 0; hh < 8; ++hh)
                ctx1[(((size_t)tc * BB + b) * 8 + hh) * DD + i] = acc[hh];
        }
    }
}

// ============ head: reduce ctx partials + cls term, then MLP ============
__global__ __launch_bounds__(256) void k_head(const float* __restrict__ ctx1,
                                              const float* __restrict__ att,
                                              const float* __restrict__ cls,
                                              const float* __restrict__ inw,
                                              const float* __restrict__ inb, const float* __restrict__ outw,
                                              const float* __restrict__ outb, const float* __restrict__ w1,
                                              const float* __restrict__ b1, const float* __restrict__ w2,
                                              const float* __restrict__ b2, float* __restrict__ out) {
    int b = blockIdx.x;
    __shared__ float cs[2048], ao[256], po[256], hid[128];
    int j = threadIdx.x;
    {
        float cv = cls[j];
#pragma unroll
        for (int hh = 0; hh < 8; ++hh) {
            float a = att[(size_t)(b * 8 + hh) * 1024] * cv;
#pragma unroll
            for (int tc = 0; tc < 4; ++tc)
                a += ctx1[(((size_t)tc * BB + b) * 8 + hh) * DD + j];
            cs[hh * 256 + j] = a;
        }
    }
    __syncthreads();
    {
        int hh = j >> 5;
        float a = inb[2 * DD + j];
        const float* wv = inw + (size_t)(2 * DD + j) * DD;
        for (int i = 0; i < 256; ++i) a = fmaf(wv[i], cs[hh * 256 + i], a);
        ao[j] = a;
    }
    __syncthreads();
    {
        float a = outb[j];
        for (int i = 0; i < 256; ++i) a = fmaf(outw[j * DD + i], ao[i], a);
        po[j] = a;
    }
    __syncthreads();
    if (j < 128) {
        float a = b1[j];
        for (int i = 0; i < 256; ++i) a = fmaf(w1[j * 256 + i], po[i], a);
        hid[j] = fmaxf(a, 0.f);
    }
    __syncthreads();
    if (j == 0) {
        float a = b2[0];
        for (int i = 0; i < 128; ++i) a = fmaf(w2[i], hid[i], a);
        out[b] = a;
    }
}

extern "C" void kernel_launch(void* const* d_in, const int* in_sizes, int n_in,
                              void* d_out, int out_size, void* d_ws, size_t ws_size,
                              hipStream_t stream) {
    (void)in_sizes; (void)n_in; (void)out_size; (void)ws_size;
    const float* x        = (const float*)d_in[0];
    const float* w_in     = (const float*)d_in[1];
    const float* b_in     = (const float*)d_in[2];
    const float* ln_in_g  = (const float*)d_in[3];
    const float* ln_in_b  = (const float*)d_in[4];
    const float* s4B      = (const float*)d_in[5];
    const float* s4C      = (const float*)d_in[6];
    const float* s4logdt  = (const float*)d_in[7];
    const float* s4D      = (const float*)d_in[8];
    const float* ln_g     = (const float*)d_in[9];
    const float* ln_b     = (const float*)d_in[10];
    const float* cls      = (const float*)d_in[11];
    const float* mha_in_w = (const float*)d_in[12];
    const float* mha_in_b = (const float*)d_in[13];
    const float* mha_out_w= (const float*)d_in[14];
    const float* mha_out_b= (const float*)d_in[15];
    const float* head_w1  = (const float*)d_in[16];
    const float* head_b1  = (const float*)d_in[17];
    const float* head_w2  = (const float*)d_in[18];
    const float* head_b2  = (const float*)d_in[19];

    float* ws   = (float*)d_ws;
    float* h    = ws + OFF_H;
    float* kker = ws + OFF_K;
    float* invn = ws + OFF_INV;
    float* P  = h;                 // 33 * 4096
    float* Q  = h + 540672;        // 32 * 4096
    float* Lb = h + 1064960;
    float* Rb = h + 3162112;
    float* qkb  = ws + OFF_MHA;
    float* qbb  = qkb + 2048;
    float* scb  = qbb + 16;        // reused: whi/wlo (pre-embed), ctx1 (post-softmax)
    float* attb = scb + 262144;
    unsigned short* whi = (unsigned short*)scb;
    unsigned short* wlo = whi + 256 * 136;
    float* ctx1b = scb;

    k_build_ad<<<dim3(257), dim3(256), 0, stream>>>(s4logdt, P, w_in, whi, wlo);
    k_powers<<<dim3(62), dim3(256), 0, stream>>>(P, Q);
    k_lr<<<dim3(NLY * 64), dim3(256), 0, stream>>>(P, Q, s4B, s4C, Lb, Rb);
    k_kker<<<dim3(NLY * 256), dim3(256), 0, stream>>>(Lb, Rb, kker);

    k_embed_mfma<<<dim3(16, BB), dim3(512), 0, stream>>>(x, whi, wlo, w_in, b_in,
                                                         ln_in_g, ln_in_b, h, invn);

    for (int l = 0; l < NLY; ++l) {
        k_conv32<<<dim3(DD, 2), dim3(512), 0, stream>>>(h, kker, invn, s4D, l);
        k_ln<<<dim3(16, BB), dim3(256), 0, stream>>>(h, ln_g + l * DD, ln_b + l * DD, h, invn);
    }

    k_qprep<<<dim3(1), dim3(256), 0, stream>>>(cls, mha_in_w, mha_in_b, qkb, qbb);
    k_scores<<<dim3(8, BB), dim3(128), 0, stream>>>(h, cls, qkb, qbb, scb);
    k_softmax<<<dim3(256), dim3(256), 0, stream>>>(scb, attb);
    k_ctx1<<<dim3(8, 4, BB), dim3(256), 0, stream>>>(h, attb, ctx1b);
    k_head<<<dim3(BB), dim3(256), 0, stream>>>(ctx1b, attb, cls, mha_in_w, mha_in_b,
                                               mha_out_w, mha_out_b,
                                               head_w1, head_b1, head_w2, head_b2, (float*)d_out);
}

// Round 10
// 495.006 us; speedup vs baseline: 1.1858x; 1.0452x over previous
//
#include <hip/hip_runtime.h>

#define BB 32
#define CC 129
#define TT 1000
#define DD 256
#define NN 64
#define NLY 4

// ---------------- workspace layout (floats) ----------------
#define OFF_H    0
#define OFF_K    8192000
#define OFF_INV  9232384
#define OFF_MHA  9264384

typedef __attribute__((ext_vector_type(8))) short bf16x8;
typedef __attribute__((ext_vector_type(8))) _Float16 f16x8;
typedef __attribute__((ext_vector_type(4))) float f32x4;
typedef __attribute__((ext_vector_type(16))) float f32x16;

__device__ __forceinline__ unsigned short f2bf(float x) {
    unsigned int u = __float_as_uint(x);
    unsigned int r = (u + 0x7FFF + ((u >> 16) & 1)) >> 16;
    return (unsigned short)r;
}
__device__ __forceinline__ float bf2f(unsigned short b) {
    return __uint_as_float(((unsigned int)b) << 16);
}
__device__ __forceinline__ unsigned short f2h(float x) {
    _Float16 v = (_Float16)x;
    return *(unsigned short*)&v;
}
__device__ __forceinline__ float h2f(unsigned short b) {
    _Float16 v = *(_Float16*)&b;
    return (float)v;
}

// ============ Ad build (block 0) + w_in prep (1..256) + MHA qprep (257) ============
// Sherman-Morrison + Newton polish (HW-verified R4/R7/R8). qprep absorbed as
// block 257 — depends only on kernel inputs; code identical to old k_qprep.
#define BST 68
__global__ __launch_bounds__(256, 1) void k_build_ad(const float* __restrict__ logdt,
                                                     float* __restrict__ P,
                                                     const float* __restrict__ w_in,
                                                     unsigned short* __restrict__ whi,
                                                     unsigned short* __restrict__ wlo,
                                                     const float* __restrict__ cls,
                                                     const float* __restrict__ inw,
                                                     const float* __restrict__ inb,
                                                     float* __restrict__ qk,
                                                     float* __restrict__ qb) {
    int tid = threadIdx.x;
    if (blockIdx.x == 257) {           // ---- qprep path (verbatim old k_qprep) ----
        __shared__ float Qv[256];
        int j = tid;
        float a = inb[j];
        for (int i = 0; i < 256; ++i) a = fmaf(inw[j * DD + i], cls[i], a);
        Qv[j] = a;
        __syncthreads();
        const float scale = 0.17677669529663687f; // 1/sqrt(32)
        for (int idx = tid; idx < 8 * 256; idx += 256) {
            int hh = idx >> 8, i = idx & 255;
            float s = 0.f;
            for (int jj = 0; jj < 32; ++jj)
                s = fmaf(Qv[hh * 32 + jj], inw[(DD + hh * 32 + jj) * DD + i], s);
            qk[idx] = s * scale;
        }
        if (tid < 8) {
            int hh = tid;
            float s = 0.f;
            for (int jj = 0; jj < 32; ++jj)
                s = fmaf(Qv[hh * 32 + jj], inb[DD + hh * 32 + jj], s);
            qb[hh] = s * scale;
        }
        return;
    }
    if (blockIdx.x != 0) {             // ---- w_in split-bf16 prep ----
        int d = blockIdx.x - 1;      // 0..255
        int c = tid;
        if (c < 136) {
            float v = (c < CC) ? w_in[d * CC + c] : 0.f;
            unsigned short h = f2bf(v);
            whi[d * 136 + c] = h;
            wlo[d * 136 + c] = f2bf(v - bf2f(h));
        }
        return;
    }
    __shared__ __align__(16) float Ms[64 * BST];
    __shared__ __align__(16) float Vs[64 * BST];
    __shared__ __align__(16) float Ws[64 * BST];
    float dt = expf(logdt[0]);
    dt = fminf(fmaxf(dt, 1e-4f), 0.1f);
    float hh = dt * 0.5f;
    int w = tid >> 6, r = tid & 63;
    {
        float Pr = sqrtf(1.f + 2.f * (float)r);
#pragma unroll
        for (int jj = 0; jj < 16; ++jj) {
            int j = w * 16 + jj;
            float av;
            if (r == j) av = -((float)r + 0.5f);
            else { float m = Pr * sqrtf(1.f + 2.f * (float)j); av = (r > j) ? -m : m; }
            Ms[r * BST + j] = ((r == j) ? 1.f : 0.f) - hh * av;
        }
    }
    if (tid < 64) {
        int lane = tid;
        float x[64], u[64];
        float s = 0.f, su = 0.f;
#pragma unroll
        for (int i = 0; i < 64; ++i) {
            const float Pi = sqrtf(2.f * (float)i + 1.f);
            float Lii = fmaf(3.f * ((float)i + 0.5f), hh, 1.f);
            float rinv = 1.f / Lii;
            float c = 2.f * hh * Pi;
            float del = (lane == i) ? 1.f : 0.f;
            x[i] = (del - c * s) * rinv;
            s = fmaf(Pi, x[i], s);
            u[i] = (Pi - c * su) * rinv;
            su = fmaf(Pi, u[i], su);
        }
        float beta = hh / (1.f - hh * su);
        float bv = beta * s;
#pragma unroll
        for (int i = 0; i < 64; ++i)
            Vs[i * BST + lane] = fmaf(bv, u[i], x[i]);
    }
    __syncthreads();
    // ---- Newton refine, step A: W = 2I - M*V ----
    {
        int tr = (tid >> 4) << 2, tc = (tid & 15) << 2;
        float acc[4][4];
#pragma unroll
        for (int u = 0; u < 4; ++u)
#pragma unroll
            for (int v = 0; v < 4; ++v) acc[u][v] = 0.f;
        for (int k0 = 0; k0 < 64; k0 += 4) {
            f32x4 av[4], bv[4];
#pragma unroll
            for (int u = 0; u < 4; ++u) av[u] = *(const f32x4*)&Ms[(tr + u) * BST + k0];
#pragma unroll
            for (int kk = 0; kk < 4; ++kk) bv[kk] = *(const f32x4*)&Vs[(k0 + kk) * BST + tc];
#pragma unroll
            for (int u = 0; u < 4; ++u)
#pragma unroll
                for (int kk = 0; kk < 4; ++kk)
#pragma unroll
                    for (int v = 0; v < 4; ++v)
                        acc[u][v] = fmaf(av[u][kk], bv[kk][v], acc[u][v]);
        }
        __syncthreads();
#pragma unroll
        for (int u = 0; u < 4; ++u)
#pragma unroll
            for (int v = 0; v < 4; ++v)
                Ws[(tr + u) * BST + tc + v] =
                    (((tr + u) == (tc + v)) ? 2.f : 0.f) - acc[u][v];
    }
    __syncthreads();
    // ---- Newton refine, step B: Ad = 2*(V*W) - I ; also P[0] = I ----
    {
        int tr = (tid >> 4) << 2, tc = (tid & 15) << 2;
        float acc[4][4];
#pragma unroll
        for (int u = 0; u < 4; ++u)
#pragma unroll
            for (int v = 0; v < 4; ++v) acc[u][v] = 0.f;
        for (int k0 = 0; k0 < 64; k0 += 4) {
            f32x4 av[4], bv[4];
#pragma unroll
            for (int u = 0; u < 4; ++u) av[u] = *(const f32x4*)&Vs[(tr + u) * BST + k0];
#pragma unroll
            for (int kk = 0; kk < 4; ++kk) bv[kk] = *(const f32x4*)&Ws[(k0 + kk) * BST + tc];
#pragma unroll
            for (int u = 0; u < 4; ++u)
#pragma unroll
                for (int kk = 0; kk < 4; ++kk)
#pragma unroll
                    for (int v = 0; v < 4; ++v)
                        acc[u][v] = fmaf(av[u][kk], bv[kk][v], acc[u][v]);
        }
#pragma unroll
        for (int u = 0; u < 4; ++u)
#pragma unroll
            for (int v = 0; v < 4; ++v) {
                int rr = tr + u, cc = tc + v;
                float eye = (rr == cc) ? 1.f : 0.f;
                P[rr * 64 + cc] = eye;
                P[4096 + rr * 64 + cc] = 2.f * acc[u][v] - eye;
            }
    }
}

// ============ single-launch power table: P[j]=Ad^j (j=2..31), Q[i]=Ad^(32i) (i=0..31) ====
// v2: 512 threads (8 waves), 2x4-output tiles — per-element k-summation order
// UNCHANGED (bitwise-identical P/Q); 2x latency hiding on the serial mm64x chain.
#define PLDA 68
__device__ __forceinline__ void mm64x(float* D, const float* A, const float* B) {
    int tr = (threadIdx.x >> 4) << 1, tc = (threadIdx.x & 15) << 2;
    float acc[2][4];
#pragma unroll
    for (int u = 0; u < 2; ++u)
#pragma unroll
        for (int v = 0; v < 4; ++v) acc[u][v] = 0.f;
#pragma unroll 2
    for (int k0 = 0; k0 < 64; k0 += 4) {
        f32x4 av[2], bv[4];
#pragma unroll
        for (int u = 0; u < 2; ++u) av[u] = *(const f32x4*)&A[(tr + u) * PLDA + k0];
#pragma unroll
        for (int kk = 0; kk < 4; ++kk) bv[kk] = *(const f32x4*)&B[(k0 + kk) * PLDA + tc];
#pragma unroll
        for (int u = 0; u < 2; ++u)
#pragma unroll
            for (int kk = 0; kk < 4; ++kk)
#pragma unroll
                for (int v = 0; v < 4; ++v)
                    acc[u][v] = fmaf(av[u][kk], bv[kk][v], acc[u][v]);
    }
    __syncthreads();
#pragma unroll
    for (int u = 0; u < 2; ++u)
#pragma unroll
        for (int v = 0; v < 4; ++v) D[(tr + u) * PLDA + tc + v] = acc[u][v];
    __syncthreads();
}

__device__ float* powm(float* U, float* V, const float* base, int e) {
    for (int i = threadIdx.x; i < 4096; i += 512)
        U[(i >> 6) * PLDA + (i & 63)] = base[(i >> 6) * PLDA + (i & 63)];
    __syncthreads();
    float* X = U; float* Y = V;
    for (int bit = 30 - __builtin_clz(e); bit >= 0; --bit) {
        mm64x(Y, X, X); { float* t = X; X = Y; Y = t; }
        if ((e >> bit) & 1) { mm64x(Y, X, base); float* t = X; X = Y; Y = t; }
    }
    return X;
}

__global__ __launch_bounds__(512) void k_powers(float* __restrict__ P, float* __restrict__ Q) {
    __shared__ __align__(16) float AdS[64 * PLDA];
    __shared__ __align__(16) float BaseS[64 * PLDA];
    __shared__ __align__(16) float Ub[64 * PLDA];
    __shared__ __align__(16) float Vb[64 * PLDA];
    int tid = threadIdx.x, bid = blockIdx.x;
    if (bid == 61) {   // Q[0] = I
        for (int i = tid; i < 4096; i += 512) Q[i] = ((i >> 6) == (i & 63)) ? 1.f : 0.f;
        return;
    }
    const float* Ad = P + 4096;
    for (int i = tid; i < 4096; i += 512) AdS[(i >> 6) * PLDA + (i & 63)] = Ad[i];
    __syncthreads();
    float* res;
    float* out;
    if (bid < 30) {                    // P[2+bid] = Ad^(2+bid)
        res = powm(Ub, Vb, AdS, bid + 2);
        out = P + (size_t)(bid + 2) * 4096;
    } else {                           // Q[i] = (Ad^32)^i, i = bid-29 in 1..31
        int iq = bid - 29;
        float* b32 = powm(Ub, Vb, AdS, 32);
        for (int i = tid; i < 4096; i += 512)
            BaseS[(i >> 6) * PLDA + (i & 63)] = b32[(i >> 6) * PLDA + (i & 63)];
        __syncthreads();
        res = powm(Ub, Vb, BaseS, iq);
        out = Q + (size_t)iq * 4096;
    }
    for (int i = tid; i < 4096; i += 512) out[i] = res[(i >> 6) * PLDA + (i & 63)];
}

// ============ L / R ============
__global__ __launch_bounds__(256) void k_lr(const float* __restrict__ P, const float* __restrict__ Q,
                                            const float* __restrict__ s4B, const float* __restrict__ s4C,
                                            float* __restrict__ L, float* __restrict__ R) {
    __shared__ float Ms[4096];
    int l = blockIdx.x >> 6, rem = blockIdx.x & 63, which = rem >> 5, idx = rem & 31;
    const float* M = which ? (P + (size_t)idx * 4096)
                           : (Q + (size_t)idx * 4096);
    for (int i = threadIdx.x; i < 4096; i += 256) Ms[i] = M[i];
    __syncthreads();
    int d = threadIdx.x;
    if (which == 0) {
        float* dst = L + (((size_t)(l * DD + d) * 32 + idx) * 64);
        for (int jc = 0; jc < 8; ++jc) {
            float acc[8];
#pragma unroll
            for (int u = 0; u < 8; ++u) acc[u] = 0.f;
            for (int i = 0; i < 64; ++i) {
                float bv = s4B[(l * NN + i) * DD + d];
#pragma unroll
                for (int u = 0; u < 8; ++u)
                    acc[u] = fmaf(bv, Ms[i * 64 + jc * 8 + u], acc[u]);
            }
#pragma unroll
            for (int u = 0; u < 8; ++u) dst[jc * 8 + u] = acc[u];
        }
    } else {
        float* dst = R + (((size_t)(l * DD + d) * 32 + idx) * 64);
        const float* Cp = s4C + (size_t)(l * DD + d) * NN;
        for (int ic = 0; ic < 8; ++ic) {
            float acc[8];
#pragma unroll
            for (int u = 0; u < 8; ++u) acc[u] = 0.f;
            for (int j = 0; j < 64; ++j) {
                float cv = Cp[j];
#pragma unroll
                for (int u = 0; u < 8; ++u)
                    acc[u] = fmaf(Ms[(ic * 8 + u) * 64 + j], cv, acc[u]);
            }
#pragma unroll
            for (int u = 0; u < 8; ++u) dst[ic * 8 + u] = acc[u];
        }
    }
}

// ============ kernel assembly ============
__global__ __launch_bounds__(256) void k_kker(const float* __restrict__ L, const float* __restrict__ R,
                                              float* __restrict__ kk) {
    __shared__ float Ls[32 * 65], Rs[32 * 65];
    int l = blockIdx.x >> 8, d = blockIdx.x & 255;
    const float* Lp = L + ((size_t)(l * DD + d) * 32) * 64;
    const float* Rp = R + ((size_t)(l * DD + d) * 32) * 64;
    for (int i = threadIdx.x; i < 2048; i += 256) {
        int row = i >> 6, col = i & 63;
        Ls[row * 65 + col] = Lp[i];
        Rs[row * 65 + col] = Rp[i];
    }
    __syncthreads();
    for (int t = threadIdx.x; t < TT; t += 256) {
        int kq = t >> 5, r = t & 31;
        const float* lr = &Ls[kq * 65];
        const float* rr = &Rs[r * 65];
        float a = 0.f;
#pragma unroll 8
        for (int m = 0; m < 64; ++m) a = fmaf(lr[m], rr[m], a);
        kk[(size_t)(l * DD + d) * TT + t] = a * expf(-0.01f * (float)t);
    }
}

// ============ MFMA embed + fused LayerNorm + pos-encoding + invn ============
__global__ __launch_bounds__(512, 4) void k_embed_mfma(const float* __restrict__ x,
                                                    const unsigned short* __restrict__ whi,
                                                    const unsigned short* __restrict__ wlo,
                                                    const float* __restrict__ w_in,
                                                    const float* __restrict__ b_in,
                                                    const float* __restrict__ lng,
                                                    const float* __restrict__ lnb,
                                                    float* __restrict__ h,
                                                    float* __restrict__ invn) {
    __shared__ unsigned short xs_h[64 * 130], xs_l[64 * 130];
    __shared__ float xlasts[64], w128s[256], biass[256], gs[256], bs[256];
    __shared__ float ps[64][8], ps2[64][8];
    __shared__ float mstat[64], rstat[64];
    int b = blockIdx.y, t0 = blockIdx.x * 64;
    int tid = threadIdx.x;
    for (int i = tid; i < CC * 64; i += 512) {
        int c = i >> 6, tl = i & 63;
        int t = t0 + tl;
        float v = (t < TT) ? x[(size_t)(b * CC + c) * TT + t] : 0.f;
        if (c == 128) {
            xlasts[tl] = v;
        } else {
            unsigned short hh = f2bf(v);
            xs_h[tl * 130 + c] = hh;
            xs_l[tl * 130 + c] = f2bf(v - bf2f(hh));
        }
    }
    if (tid < 256) {
        w128s[tid] = w_in[tid * CC + 128];
        biass[tid] = b_in[tid];
        gs[tid] = lng[tid];
        bs[tid] = lnb[tid];
    }
    __syncthreads();
    int wave = tid >> 6, lane = tid & 63;
    int tn = lane & 15, q = lane >> 4;
    int d0w = wave * 32;
    f32x4 acc[4][2];
#pragma unroll
    for (int nt = 0; nt < 4; ++nt)
#pragma unroll
        for (int mt = 0; mt < 2; ++mt) acc[nt][mt] = (f32x4){0.f, 0.f, 0.f, 0.f};
#pragma unroll
    for (int kc = 0; kc < 4; ++kc) {
        int c0 = kc * 32;
        bf16x8 Ah[2], Al[2];
#pragma unroll
        for (int mt = 0; mt < 2; ++mt) {
            int base = (d0w + mt * 16 + tn) * 136 + c0 + 8 * q;
            Ah[mt] = *(const bf16x8*)&whi[base];
            Al[mt] = *(const bf16x8*)&wlo[base];
        }
#pragma unroll
        for (int nt = 0; nt < 4; ++nt) {
            const unsigned int* ph = (const unsigned int*)&xs_h[(nt * 16 + tn) * 130 + c0 + 8 * q];
            const unsigned int* pl = (const unsigned int*)&xs_l[(nt * 16 + tn) * 130 + c0 + 8 * q];
            union { bf16x8 v; unsigned int u[4]; } Bh, Bl;
            Bh.u[0] = ph[0]; Bh.u[1] = ph[1]; Bh.u[2] = ph[2]; Bh.u[3] = ph[3];
            Bl.u[0] = pl[0]; Bl.u[1] = pl[1]; Bl.u[2] = pl[2]; Bl.u[3] = pl[3];
#pragma unroll
            for (int mt = 0; mt < 2; ++mt) {
                acc[nt][mt] = __builtin_amdgcn_mfma_f32_16x16x32_bf16(Al[mt], Bh.v, acc[nt][mt], 0, 0, 0);
                acc[nt][mt] = __builtin_amdgcn_mfma_f32_16x16x32_bf16(Ah[mt], Bl.v, acc[nt][mt], 0, 0, 0);
                acc[nt][mt] = __builtin_amdgcn_mfma_f32_16x16x32_bf16(Ah[mt], Bh.v, acc[nt][mt], 0, 0, 0);
            }
        }
    }
#pragma unroll
    for (int nt = 0; nt < 4; ++nt) {
        float xl = xlasts[nt * 16 + tn];
        float s = 0.f, s2 = 0.f;
#pragma unroll
        for (int mt = 0; mt < 2; ++mt) {
#pragma unroll
            for (int r = 0; r < 4; ++r) {
                int d = d0w + mt * 16 + 4 * q + r;
                float v = acc[nt][mt][r] + biass[d] + w128s[d] * xl;
                acc[nt][mt][r] = v;
                s += v; s2 = fmaf(v, v, s2);
            }
        }
        s += __shfl_xor(s, 16); s += __shfl_xor(s, 32);
        s2 += __shfl_xor(s2, 16); s2 += __shfl_xor(s2, 32);
        if (q == 0) { ps[nt * 16 + tn][wave] = s; ps2[nt * 16 + tn][wave] = s2; }
    }
    __syncthreads();
    if (tid < 64) {
        float s = 0.f, s2 = 0.f;
#pragma unroll
        for (int k = 0; k < 8; ++k) { s += ps[tid][k]; s2 += ps2[tid][k]; }
        float mean = s * (1.f / 256.f);
        float ex2 = s2 * (1.f / 256.f);
        mstat[tid] = mean;
        rstat[tid] = 1.f / sqrtf(ex2 - mean * mean + 1e-5f);
    }
    __syncthreads();
    float sq[4] = {0.f, 0.f, 0.f, 0.f};
#pragma unroll
    for (int mt = 0; mt < 2; ++mt) {
#pragma unroll
        for (int r = 0; r < 4; ++r) {
            int d = d0w + mt * 16 + 4 * q + r;
            float gd = gs[d], bd = bs[d];
            float freq = expf((float)(d & ~1) * (-9.210340371976184f / 256.f));
            int odd = d & 1;
#pragma unroll
            for (int nt = 0; nt < 4; ++nt) {
                int tl = nt * 16 + tn;
                int t = t0 + tl;
                float o = (acc[nt][mt][r] - mstat[tl]) * rstat[tl] * gd + bd;
                float ang = (float)t * freq;
                o += odd ? cosf(ang) : sinf(ang);
                if (t < TT) h[((size_t)(b * DD + d)) * TT + t] = o;
                sq[nt] = fmaf(o, o, sq[nt]);
            }
        }
    }
#pragma unroll
    for (int nt = 0; nt < 4; ++nt) {
        float s = sq[nt];
        s += __shfl_xor(s, 16); s += __shfl_xor(s, 32);
        if (q == 0) ps[nt * 16 + tn][wave] = s;
    }
    __syncthreads();
    if (tid < 64) {
        int t = t0 + tid;
        if (t < TT) {
            float s = 0.f;
#pragma unroll
            for (int k = 0; k < 8; ++k) s += ps[tid][k];
            invn[b * TT + t] = 1.f / (sqrtf(s) + 1e-8f);
        }
    }
}

// ============ LayerNorm (in-place), single-pass ============
// v1 form (HW-verified): compiler re-read of `in` is L2-hot and nearly free.
__global__ __launch_bounds__(256) void k_ln(const float* __restrict__ in, const float* __restrict__ g,
                                            const float* __restrict__ bia, float* __restrict__ out,
                                            float* __restrict__ invn) {
    int b = blockIdx.y, t0 = blockIdx.x * 64;
    int w = threadIdx.x >> 6, lane = threadIdx.x & 63;
    int t = t0 + lane;
    __shared__ float ps[4][64], ps2[4][64];
    float v[64];
    float s = 0.f, s2 = 0.f;
    bool ok = t < TT;
#pragma unroll
    for (int k = 0; k < 64; ++k) {
        float x = ok ? in[(size_t)(b * DD + (w + 4 * k)) * TT + t] : 0.f;
        v[k] = x;
        s += x; s2 = fmaf(x, x, s2);
    }
    ps[w][lane] = s; ps2[w][lane] = s2;
    __syncthreads();
    float mean = (ps[0][lane] + ps[1][lane] + ps[2][lane] + ps[3][lane]) * (1.f / 256.f);
    float ex2  = (ps2[0][lane] + ps2[1][lane] + ps2[2][lane] + ps2[3][lane]) * (1.f / 256.f);
    float rstd = 1.f / sqrtf(ex2 - mean * mean + 1e-5f);
    float sq = 0.f;
    if (ok) {
#pragma unroll
        for (int k = 0; k < 64; ++k) {
            int d = w + 4 * k;
            float o = (v[k] - mean) * rstd * g[d] + bia[d];
            out[(size_t)(b * DD + d) * TT + t] = o;
            sq = fmaf(o, o, sq);
        }
    }
    __syncthreads();
    ps[w][lane] = sq;
    __syncthreads();
    if (w == 0 && ok) {
        float tot = ps[0][lane] + ps[1][lane] + ps[2][lane] + ps[3][lane];
        invn[b * TT + t] = 1.f / (sqrtf(tot) + 1e-8f);
    }
}

__device__ __forceinline__ float gelu_exact(float y) {
    return 0.5f * y * (1.f + erff(y * 0.7071067811865476f));
}

// ============ MFMA conv v3 (HW-verified R8): safe 16-batch split, grid (DD, 2) ============
#define XS2 1032
__global__ __launch_bounds__(512) void k_conv32(float* __restrict__ h, const float* __restrict__ kk,
                                                const float* __restrict__ invn,
                                                const float* __restrict__ s4D, int layer) {
    __shared__ unsigned short Xs[16 * XS2];
    __shared__ unsigned int pks[1056];
    int d = blockIdx.x;
    int bbase = blockIdx.y * 16;
    int tid = threadIdx.x;
    const float* krow = kk + (size_t)(layer * DD + d) * TT;
    for (int mm = tid; mm < 1056; mm += 512) {
        int m = mm - 32;
        float klo = (m >= 0 && m < TT) ? krow[m] : 0.f;
        float kpr = (m >= 1 && m <= TT) ? krow[m - 1] : 0.f;
        pks[mm] = (unsigned int)f2h(klo) | ((unsigned int)f2h(kpr) << 16);
    }
    for (int ii = tid; ii < 16 * 512; ii += 512) {
        int bb = ii >> 9;                       // 0..15 local batch
        int tp = (ii & 511) * 2;
        const float* hrow = h + ((size_t)(bbase + bb) * DD + d) * TT;
        const float* ivr = invn + (size_t)(bbase + bb) * TT;
        float v0 = (tp < TT) ? hrow[tp] * ivr[tp] : 0.f;
        float v1 = (tp + 1 < TT) ? hrow[tp + 1] * ivr[tp + 1] : 0.f;
        ((unsigned int*)Xs)[(bb * XS2 + tp) >> 1] = (unsigned int)f2h(v0) | ((unsigned int)f2h(v1) << 16);
    }
    __syncthreads();
    float gate = 1.f / (1.f + expf(-s4D[layer * DD + d]));
    int wave = tid >> 6, lane = tid & 63;
    int nn = lane & 31, kq8 = (lane >> 5) << 3;
    int bp = nn & 15;                           // A-row batch (rows 16-31 duplicate 0-15)
    for (int pass = 0; pass < 2; ++pass) {
        int G = pass ? (15 - wave) : wave;
        int jlo = 2 * G;
        f32x16 acc[2];
#pragma unroll
        for (int m = 0; m < 2; ++m)
#pragma unroll
            for (int r = 0; r < 16; ++r) acc[m][r] = 0.f;
        for (int D = 32 * jlo + 32; D >= -16; D -= 16) {
            int S32 = D + nn - kq8 + 32;
            union { f16x8 v; unsigned int u[4]; } bh;
            bh.u[0] = pks[S32];
            bh.u[1] = pks[S32 - 2];
            bh.u[2] = pks[S32 - 4];
            bh.u[3] = pks[S32 - 6];
#pragma unroll
            for (int m = 0; m < 2; ++m) {
                int u0 = (jlo + m) * 32 - D;
                if (u0 >= 0) {
                    const f16x8 ah = *(const f16x8*)&Xs[bp * XS2 + u0 + kq8];
                    acc[m] = __builtin_amdgcn_mfma_f32_32x32x16_f16(ah, bh.v, acc[m], 0, 0, 0);
                }
            }
        }
#pragma unroll
        for (int m = 0; m < 2; ++m) {
            int t = (jlo + m) * 32 + nn;
            if (t < TT) {
#pragma unroll
                for (int r = 0; r < 16; ++r) {
                    int brow = (r & 3) + 8 * (r >> 2) + 4 * (lane >> 5);
                    if (brow < 16) {            // rows 16-31 are discarded duplicates
                        size_t ix = ((size_t)(bbase + brow) * DD + d) * TT + t;
                        float y = acc[m][r];
                        float xn = h2f(Xs[brow * XS2 + t]);
                        float ho = h[ix];       // L2-hot re-read (exact residual)
                        h[ix] = gelu_exact(y + xn * gate) + 1.1f * ho;
                    }
                }
            }
        }
    }
}

// ============ MHA scores ============
__global__ __launch_bounds__(128) void k_scores(const float* __restrict__ h, const float* __restrict__ cls,
                                                const float* __restrict__ qkw, const float* __restrict__ qbw,
                                                float* __restrict__ sc) {
    __shared__ float qks[8 * 256];
    int b = blockIdx.y;
    int s = blockIdx.x * 128 + threadIdx.x;
    for (int i = threadIdx.x; i < 2048; i += 128) qks[i] = qkw[i];
    __syncthreads();
    if (s >= TT + 1) return;
    float acc[8];
#pragma unroll
    for (int hh = 0; hh < 8; ++hh) acc[hh] = qbw[hh];
    if (s == 0) {
        for (int i = 0; i < 256; ++i) {
            float v = cls[i];
#pragma unroll
            for (int hh = 0; hh < 8; ++hh) acc[hh] = fmaf(qks[hh * 256 + i], v, acc[hh]);
        }
    } else {
        const float* hb = h + (size_t)b * DD * TT + (s - 1);
        for (int i = 0; i < 256; ++i) {
            float v = hb[(size_t)i * TT];
#pragma unroll
            for (int hh = 0; hh < 8; ++hh) acc[hh] = fmaf(qks[hh * 256 + i], v, acc[hh]);
        }
    }
#pragma unroll
    for (int hh = 0; hh < 8; ++hh) sc[(size_t)(b * 8 + hh) * 1024 + s] = acc[hh];
}

__global__ __launch_bounds__(256) void k_softmax(const float* __restrict__ sc, float* __restrict__ att) {
    int row = blockIdx.x;
    const float* p = sc + (size_t)row * 1024;
    float* o = att + (size_t)row * 1024;
    __shared__ float red[256];
    float m = -3.4e38f;
    for (int s = threadIdx.x; s < TT + 1; s += 256) m = fmaxf(m, p[s]);
    red[threadIdx.x] = m; __syncthreads();
    for (int st = 128; st; st >>= 1) {
        if (threadIdx.x < st) red[threadIdx.x] = fmaxf(red[threadIdx.x], red[threadIdx.x + st]);
        __syncthreads();
    }
    m = red[0]; __syncthreads();
    float sum = 0.f;
    for (int s = threadIdx.x; s < TT + 1; s += 256) {
        float e = expf(p[s] - m);
        o[s] = e; sum += e;
    }
    red[threadIdx.x] = sum; __syncthreads();
    for (int st = 128; st; st >>= 1) {
        if (threadIdx.x < st) red[threadIdx.x] += red[threadIdx.x + st];
        __syncthreads();
    }
    float inv = 1.f / red[0];
    for (int s = threadIdx.x; s < TT + 1; s += 256) o[s] *= inv;
}

// ============ ctx stage 1: t-chunked partials ============
__global__ __launch_bounds__(256) void k_ctx1(const float* __restrict__ h,
                                              const float* __restrict__ att,
                                              float* __restrict__ ctx1) {
    __shared__ float as[8][256];
    int i0 = blockIdx.x * 32, tc = blockIdx.y, b = blockIdx.z;
    int tid = threadIdx.x;
    int sbase = tc * 250 + 1;
    for (int idx = tid; idx < 2048; idx += 256) {
        int hh = idx >> 8, u = idx & 255;
        as[hh][u] = (u < 250) ? att[(size_t)(b * 8 + hh) * 1024 + sbase + u] : 0.f;
    }
    __syncthreads();
    int w = tid >> 6, lane = tid & 63;
    for (int ii = 0; ii < 8; ++ii) {
        int i = i0 + w * 8 + ii;
        const float* hb = h + ((size_t)(b * DD + i)) * TT + tc * 250;
        float acc[8];
#pragma unroll
        for (int hh = 0; hh < 8; ++hh) acc[hh] = 0.f;
        for (int u = lane; u < 250; u += 64) {
            float v = hb[u];
#pragma unroll
            for (int hh = 0; hh < 8; ++hh) acc[hh] = fmaf(as[hh][u], v, acc[hh]);
        }
#pragma unroll
        for (int off = 32; off; off >>= 1)
#pragma unroll
            for (int hh = 0; hh < 8; ++hh) acc[hh] += __shfl_down(acc[hh], off);
        if (lane == 0) {
#pragma unroll
            for (int hh = 0; hh < 8; ++hh)
                ctx1[(((size_t)tc * BB + b) * 8 + hh) * DD + i] = acc[hh];
        }
    }
}

// ============ head: reduce ctx partials + cls term, then MLP ============
__global__ __launch_bounds__(256) void k_head(const float* __restrict__ ctx1,
                                              const float* __restrict__ att,
                                              const float* __restrict__ cls,
                                              const float* __restrict__ inw,
                                              const float* __restrict__ inb, const float* __restrict__ outw,
                                              const float* __restrict__ outb, const float* __restrict__ w1,
                                              const float* __restrict__ b1, const float* __restrict__ w2,
                                              const float* __restrict__ b2, float* __restrict__ out) {
    int b = blockIdx.x;
    __shared__ float cs[2048], ao[256], po[256], hid[128];
    int j = threadIdx.x;
    {
        float cv = cls[j];
#pragma unroll
        for (int hh = 0; hh < 8; ++hh) {
            float a = att[(size_t)(b * 8 + hh) * 1024] * cv;
#pragma unroll
            for (int tc = 0; tc < 4; ++tc)
                a += ctx1[(((size_t)tc * BB + b) * 8 + hh) * DD + j];
            cs[hh * 256 + j] = a;
        }
    }
    __syncthreads();
    {
        int hh = j >> 5;
        float a = inb[2 * DD + j];
        const float* wv = inw + (size_t)(2 * DD + j) * DD;
        for (int i = 0; i < 256; ++i) a = fmaf(wv[i], cs[hh * 256 + i], a);
        ao[j] = a;
    }
    __syncthreads();
    {
        float a = outb[j];
        for (int i = 0; i < 256; ++i) a = fmaf(outw[j * DD + i], ao[i], a);
        po[j] = a;
    }
    __syncthreads();
    if (j < 128) {
        float a = b1[j];
        for (int i = 0; i < 256; ++i) a = fmaf(w1[j * 256 + i], po[i], a);
        hid[j] = fmaxf(a, 0.f);
    }
    __syncthreads();
    if (j == 0) {
        float a = b2[0];
        for (int i = 0; i < 128; ++i) a = fmaf(w2[i], hid[i], a);
        out[b] = a;
    }
}

extern "C" void kernel_launch(void* const* d_in, const int* in_sizes, int n_in,
                              void* d_out, int out_size, void* d_ws, size_t ws_size,
                              hipStream_t stream) {
    (void)in_sizes; (void)n_in; (void)out_size; (void)ws_size;
    const float* x        = (const float*)d_in[0];
    const float* w_in     = (const float*)d_in[1];
    const float* b_in     = (const float*)d_in[2];
    const float* ln_in_g  = (const float*)d_in[3];
    const float* ln_in_b  = (const float*)d_in[4];
    const float* s4B      = (const float*)d_in[5];
    const float* s4C      = (const float*)d_in[6];
    const float* s4logdt  = (const float*)d_in[7];
    const float* s4D      = (const float*)d_in[8];
    const float* ln_g     = (const float*)d_in[9];
    const float* ln_b     = (const float*)d_in[10];
    const float* cls      = (const float*)d_in[11];
    const float* mha_in_w = (const float*)d_in[12];
    const float* mha_in_b = (const float*)d_in[13];
    const float* mha_out_w= (const float*)d_in[14];
    const float* mha_out_b= (const float*)d_in[15];
    const float* head_w1  = (const float*)d_in[16];
    const float* head_b1  = (const float*)d_in[17];
    const float* head_w2  = (const float*)d_in[18];
    const float* head_b2  = (const float*)d_in[19];

    float* ws   = (float*)d_ws;
    float* h    = ws + OFF_H;
    float* kker = ws + OFF_K;
    float* invn = ws + OFF_INV;
    float* P  = h;                 // 33 * 4096
    float* Q  = h + 540672;        // 32 * 4096
    float* Lb = h + 1064960;
    float* Rb = h + 3162112;
    float* qkb  = ws + OFF_MHA;
    float* qbb  = qkb + 2048;
    float* scb  = qbb + 16;        // reused: whi/wlo (pre-embed), ctx1 (post-softmax)
    float* attb = scb + 262144;
    unsigned short* whi = (unsigned short*)scb;
    unsigned short* wlo = whi + 256 * 136;
    float* ctx1b = scb;

    k_build_ad<<<dim3(258), dim3(256), 0, stream>>>(s4logdt, P, w_in, whi, wlo,
                                                    cls, mha_in_w, mha_in_b, qkb, qbb);
    k_powers<<<dim3(62), dim3(512), 0, stream>>>(P, Q);
    k_lr<<<dim3(NLY * 64), dim3(256), 0, stream>>>(P, Q, s4B, s4C, Lb, Rb);
    k_kker<<<dim3(NLY * 256), dim3(256), 0, stream>>>(Lb, Rb, kker);

    k_embed_mfma<<<dim3(16, BB), dim3(512), 0, stream>>>(x, whi, wlo, w_in, b_in,
                                                         ln_in_g, ln_in_b, h, invn);

    for (int l = 0; l < NLY; ++l) {
        k_conv32<<<dim3(DD, 2), dim3(512), 0, stream>>>(h, kker, invn, s4D, l);
        k_ln<<<dim3(16, BB), dim3(256), 0, stream>>>(h, ln_g + l * DD, ln_b + l * DD, h, invn);
    }

    k_scores<<<dim3(8, BB), dim3(128), 0, stream>>>(h, cls, qkb, qbb, scb);
    k_softmax<<<dim3(256), dim3(256), 0, stream>>>(scb, attb);
    k_ctx1<<<dim3(8, 4, BB), dim3(256), 0, stream>>>(h, attb, ctx1b);
    k_head<<<dim3(BB), dim3(256), 0, stream>>>(ctx1b, attb, cls, mha_in_w, mha_in_b,
                                               mha_out_w, mha_out_b,
                                               head_w1, head_b1, head_w2, head_b2, (float*)d_out);
}